// Round 16
// baseline (13206.239 us; speedup 1.0000x reference)
//
#include <hip/hip_runtime.h>
#include <hip/hip_bf16.h>
#include <stdint.h>

#define SEQ   1024
#define NB    4
#define BT    4096
#define DM    512
#define DI    1024
#define NL    6
#define CHUNK 64
#define NCH   16          // SEQ/CHUNK
#define NSLOT (NL + NCH - 1)

typedef float  f32x4  __attribute__((ext_vector_type(4)));
typedef short  bf16x8 __attribute__((ext_vector_type(8)));
typedef _Float16 f16x2 __attribute__((ext_vector_type(2)));
typedef uint32_t u32x4 __attribute__((ext_vector_type(4)));

__device__ __forceinline__ float bf2f(unsigned short u){
  union { unsigned int i; float f; } v; v.i = ((unsigned int)u) << 16; return v.f;
}
__device__ __forceinline__ unsigned short f2bf(float f){
  union { float f; unsigned int i; } v; v.f = f;
  unsigned int x = v.i;
  return (unsigned short)((x + 0x7fffu + ((x >> 16) & 1u)) >> 16);
}
__device__ __forceinline__ float bits2f(uint32_t u){
  union { uint32_t i; float f; } v; v.i = u; return v.f;
}
__device__ __forceinline__ f16x2 u2h(uint32_t u){
  union { uint32_t u; f16x2 h; } v; v.u = u; return v.h;
}
__device__ __forceinline__ uint32_t pkrtz2u(float a, float b){
  union { __fp16 __attribute__((ext_vector_type(2))) h; uint32_t u; } v;
  v.h = __builtin_amdgcn_cvt_pkrtz(a, b);
  return v.u;
}
__device__ __forceinline__ uint32_t packf16(float a, float b){
  union { _Float16 h[2]; uint32_t u; } v;
  v.h[0] = (_Float16)a; v.h[1] = (_Float16)b; return v.u;
}
__device__ __forceinline__ float sigmoidf_(float x){ return __fdividef(1.f, 1.f + __expf(-x)); }
__device__ __forceinline__ float siluf_(float x){ return x * __fdividef(1.f, 1.f + __expf(-x)); }
__device__ __forceinline__ float tanhf_(float x){
  float e = __expf(2.f*x);
  return 1.f - __fdividef(2.f, e + 1.f);
}

// ---- whh f32 -> thread-major packed f16, dwordx4-granular (512-thr wgs, 32 wgs/layer) ----
// u32x4 idx = ((l*32+g)*24 + j4)*512 + tid; thread (il=tid>>4 in 0..31, ks=tid&15),
// i = g*32+il; j4 = G*8+qq covers k = ks*64 + qq*8 + {0..7}.
__global__ __launch_bounds__(256) void cvtwt_kernel(const float* __restrict__ whh,
                                                    uint32_t* __restrict__ wT){
  const int n4 = NL*32*24*512;
  u32x4* out4 = (u32x4*)wT;
  for (int idx = blockIdx.x*256 + threadIdx.x; idx < n4; idx += gridDim.x*256){
    int tid = idx & 511;
    int rest = idx >> 9;
    int j4 = rest % 24;
    int rest2 = rest / 24;
    int g = rest2 & 31;
    int l = rest2 >> 5;
    int il = tid >> 4, ks = tid & 15;
    int i = g*32 + il;
    int G = j4 >> 3, qq = j4 & 7;
    int kb = ks*64 + qq*8;
    const float* src = whh + ((size_t)l*3072 + G*1024 + i)*1024 + kb;
    u32x4 v;
    v[0] = packf16(src[0], src[1]);
    v[1] = packf16(src[2], src[3]);
    v[2] = packf16(src[4], src[5]);
    v[3] = packf16(src[6], src[7]);
    out4[idx] = v;
  }
}

// ---- per-slot fused residual+LN ----
__global__ __launch_bounds__(256) void lnres_slot(
    int slot, const float* __restrict__ x,
    const float* __restrict__ norm_w, const float* __restrict__ norm_b,
    float* __restrict__ hidden_ring,   // [NL][2][256][512]
    float* __restrict__ resid_ring,    // [NL][2][256][512]
    float* __restrict__ resid5,        // [4096][512]
    unsigned short* __restrict__ lnbf) // [NL][256][512]
{
  const int l = blockIdx.z, c = slot - l;
  if (c < 0 || c >= NCH) return;
  const int wave = threadIdx.x >> 6;
  const int lane = threadIdx.x & 63;
  const int r = blockIdx.x*4 + wave;
  const int b = r >> 6, dt = r & 63;
  const int tg = c*CHUNK + dt;
  const int p = c & 1;

  const float* hid = (l == 0) ? x + ((size_t)b*SEQ + tg)*DM + lane*8
                              : hidden_ring + (((size_t)(l-1)*2 + p)*256 + r)*DM + lane*8;
  float4 a0 = *(const float4*)hid;
  float4 a1 = *(const float4*)(hid + 4);
  if (l > 0){
    const float* rin = resid_ring + (((size_t)(l-1)*2 + p)*256 + r)*DM + lane*8;
    float4 b0 = *(const float4*)rin;
    float4 b1 = *(const float4*)(rin + 4);
    a0.x+=b0.x; a0.y+=b0.y; a0.z+=b0.z; a0.w+=b0.w;
    a1.x+=b1.x; a1.y+=b1.y; a1.z+=b1.z; a1.w+=b1.w;
  }
  float* rout = (l == 5) ? resid5 + ((size_t)b*SEQ + tg)*DM + lane*8
                         : resid_ring + (((size_t)l*2 + p)*256 + r)*DM + lane*8;
  *(float4*)rout = a0;
  *(float4*)(rout + 4) = a1;

  float xv[8] = {a0.x,a0.y,a0.z,a0.w,a1.x,a1.y,a1.z,a1.w};
  float s = 0.f, sq = 0.f;
  #pragma unroll
  for (int q=0;q<8;q++){ s += xv[q]; sq += xv[q]*xv[q]; }
  #pragma unroll
  for (int off=32; off; off>>=1){ s += __shfl_xor(s, off); sq += __shfl_xor(sq, off); }
  float mean = s * (1.f/DM);
  float var  = sq * (1.f/DM) - mean*mean;
  float rstd = rsqrtf(var + 1e-5f);
  const float* gamma = norm_w + l*DM;
  const float* beta  = norm_b + l*DM;
  float4 g0 = *(const float4*)(gamma + lane*8);
  float4 g1 = *(const float4*)(gamma + lane*8 + 4);
  float4 e0 = *(const float4*)(beta  + lane*8);
  float4 e1 = *(const float4*)(beta  + lane*8 + 4);
  float gv[8] = {g0.x,g0.y,g0.z,g0.w,g1.x,g1.y,g1.z,g1.w};
  float ev[8] = {e0.x,e0.y,e0.z,e0.w,e1.x,e1.y,e1.z,e1.w};
  uint4 pk;
  float y0 = (xv[0]-mean)*rstd*gv[0]+ev[0], y1 = (xv[1]-mean)*rstd*gv[1]+ev[1];
  float y2 = (xv[2]-mean)*rstd*gv[2]+ev[2], y3 = (xv[3]-mean)*rstd*gv[3]+ev[3];
  float y4 = (xv[4]-mean)*rstd*gv[4]+ev[4], y5 = (xv[5]-mean)*rstd*gv[5]+ev[5];
  float y6 = (xv[6]-mean)*rstd*gv[6]+ev[6], y7 = (xv[7]-mean)*rstd*gv[7]+ev[7];
  pk.x = (unsigned)f2bf(y0) | ((unsigned)f2bf(y1)<<16);
  pk.y = (unsigned)f2bf(y2) | ((unsigned)f2bf(y3)<<16);
  pk.z = (unsigned)f2bf(y4) | ((unsigned)f2bf(y5)<<16);
  pk.w = (unsigned)f2bf(y6) | ((unsigned)f2bf(y7)<<16);
  *(uint4*)(lnbf + ((size_t)l*256 + r)*DM + lane*8) = pk;
}

// ---- final layernorm (full 4096 rows) ----
__global__ __launch_bounds__(256) void ln_final(
    const float* __restrict__ hidden, const float* __restrict__ resid_in,
    const float* __restrict__ gamma,  const float* __restrict__ beta,
    float* __restrict__ out_f32)
{
  int wave = threadIdx.x >> 6;
  int lane = threadIdx.x & 63;
  int row  = blockIdx.x*4 + wave;
  size_t base = (size_t)row * DM + lane*8;
  float4 a0 = *(const float4*)(hidden + base);
  float4 a1 = *(const float4*)(hidden + base + 4);
  float4 b0 = *(const float4*)(resid_in + base);
  float4 b1 = *(const float4*)(resid_in + base + 4);
  a0.x+=b0.x; a0.y+=b0.y; a0.z+=b0.z; a0.w+=b0.w;
  a1.x+=b1.x; a1.y+=b1.y; a1.z+=b1.z; a1.w+=b1.w;
  float xv[8] = {a0.x,a0.y,a0.z,a0.w,a1.x,a1.y,a1.z,a1.w};
  float s = 0.f, sq = 0.f;
  #pragma unroll
  for (int q=0;q<8;q++){ s += xv[q]; sq += xv[q]*xv[q]; }
  #pragma unroll
  for (int off=32; off; off>>=1){ s += __shfl_xor(s, off); sq += __shfl_xor(sq, off); }
  float mean = s * (1.f/DM);
  float var  = sq * (1.f/DM) - mean*mean;
  float rstd = rsqrtf(var + 1e-5f);
  float4 g0 = *(const float4*)(gamma + lane*8);
  float4 g1 = *(const float4*)(gamma + lane*8 + 4);
  float4 e0 = *(const float4*)(beta  + lane*8);
  float4 e1 = *(const float4*)(beta  + lane*8 + 4);
  float gv[8] = {g0.x,g0.y,g0.z,g0.w,g1.x,g1.y,g1.z,g1.w};
  float ev[8] = {e0.x,e0.y,e0.z,e0.w,e1.x,e1.y,e1.z,e1.w};
  float4 o0, o1;
  o0.x=(xv[0]-mean)*rstd*gv[0]+ev[0]; o0.y=(xv[1]-mean)*rstd*gv[1]+ev[1];
  o0.z=(xv[2]-mean)*rstd*gv[2]+ev[2]; o0.w=(xv[3]-mean)*rstd*gv[3]+ev[3];
  o1.x=(xv[4]-mean)*rstd*gv[4]+ev[4]; o1.y=(xv[5]-mean)*rstd*gv[5]+ev[5];
  o1.z=(xv[6]-mean)*rstd*gv[6]+ev[6]; o1.w=(xv[7]-mean)*rstd*gv[7]+ev[7];
  *(float4*)(out_f32 + base)     = o0;
  *(float4*)(out_f32 + base + 4) = o1;
}

// ---- per-slot GEMM, A bf16 x B f32(on-the-fly->bf16)^T, M=256 ----
__device__ __forceinline__ bf16x8 ldcvt8(const float* p){
  float4 u = *(const float4*)p;
  float4 v = *(const float4*)(p + 4);
  bf16x8 r;
  r[0]=(short)f2bf(u.x); r[1]=(short)f2bf(u.y); r[2]=(short)f2bf(u.z); r[3]=(short)f2bf(u.w);
  r[4]=(short)f2bf(v.x); r[5]=(short)f2bf(v.y); r[6]=(short)f2bf(v.z); r[7]=(short)f2bf(v.w);
  return r;
}
__global__ __launch_bounds__(256) void gemm_slot(
    int op, int slot,
    const unsigned short* __restrict__ lnbf, const float* __restrict__ inw,
    const float* __restrict__ inb, float* __restrict__ xz_ring,
    const unsigned short* __restrict__ xconvb, const float* __restrict__ wih,
    const float* __restrict__ bih, unsigned short* __restrict__ xihb,
    const unsigned short* __restrict__ xoutb, const float* __restrict__ outw,
    const float* __restrict__ outb, float* __restrict__ hidden_ring,
    float* __restrict__ hidden5)
{
  const int l = blockIdx.z, c = slot - l;
  if (c < 0 || c >= NCH) return;

  const unsigned short* A; const float* Bf; const float* bias;
  int N, K;
  if (op == 0){ A = lnbf   + (size_t)l*256*DM;  Bf = inw  + (size_t)l*2048*512;  bias = inb  + l*2048; N = 2048; K = 512; }
  else if (op == 1){ A = xconvb + (size_t)l*256*DI; Bf = wih  + (size_t)l*3072*1024; bias = bih  + l*3072; N = 3072; K = 1024; }
  else { A = xoutb  + (size_t)l*256*DI; Bf = outw + (size_t)l*512*1024;  bias = outb + l*512;  N = 512;  K = 1024; }

  const int tid  = threadIdx.x;
  const int wid  = tid >> 6, lane = tid & 63;
  const int wm   = wid >> 1, wn = wid & 1;
  const int tm   = blockIdx.y*128 + wm*64;
  const int tn   = blockIdx.x*128 + wn*64;
  const int l15  = lane & 15;
  const int lk   = (lane >> 4) * 8;

  f32x4 acc[4][4] = {};
  for (int kk = 0; kk < K; kk += 32){
    bf16x8 a[4], b[4];
    #pragma unroll
    for (int f=0; f<4; ++f)
      a[f] = *(const bf16x8*)(A + (size_t)(tm + f*16 + l15)*K + kk + lk);
    #pragma unroll
    for (int f=0; f<4; ++f)
      b[f] = ldcvt8(Bf + (size_t)(tn + f*16 + l15)*K + kk + lk);
    #pragma unroll
    for (int i=0;i<4;i++)
      #pragma unroll
      for (int j=0;j<4;j++)
        acc[i][j] = __builtin_amdgcn_mfma_f32_16x16x32_bf16(a[i], b[j], acc[i][j], 0,0,0);
  }
  const int crow0 = (lane>>4)*4;
  const int p = c & 1;
  #pragma unroll
  for (int i=0;i<4;i++){
    #pragma unroll
    for (int j=0;j<4;j++){
      int col = tn + j*16 + l15;
      float bv = bias[col];
      #pragma unroll
      for (int r=0;r<4;r++){
        int row = tm + i*16 + crow0 + r;
        float val = acc[i][j][r] + bv;
        if (op == 0){
          xz_ring[(((size_t)l*2 + p)*256 + row)*2048 + col] = val;
        } else if (op == 1){
          xihb[((size_t)l*256 + row)*3072 + col] = f2bf(val);
        } else {
          if (l == 5){
            int b_ = row >> 6, dt = row & 63;
            hidden5[((size_t)b_*SEQ + c*CHUNK + dt)*DM + col] = val;
          } else {
            hidden_ring[(((size_t)l*2 + p)*256 + row)*DM + col] = val;
          }
        }
      }
    }
  }
}

// ---- per-slot causal conv(4)+SiLU ----
__global__ __launch_bounds__(256) void conv_slot(
    int slot, const float* __restrict__ xz_ring,
    const float* __restrict__ cw, const float* __restrict__ cb,
    unsigned short* __restrict__ xconvb)
{
  const int l = blockIdx.z, c = slot - l;
  if (c < 0 || c >= NCH) return;
  const int idx = blockIdx.x*256 + threadIdx.x;
  const int ch = idx & (DI-1);
  const int r  = idx >> 10;
  const int b  = r >> 6, dt = r & 63;
  const int tg = c*CHUNK + dt;
  const int p  = c & 1;

  const float* base = xz_ring + ((size_t)l*2)*256*2048;
  float w0 = cw[(l*DI + ch)*4+0], w1 = cw[(l*DI + ch)*4+1];
  float w2 = cw[(l*DI + ch)*4+2], w3 = cw[(l*DI + ch)*4+3];
  float acc = cb[l*DI + ch] + base[((size_t)p*256 + r)*2048 + ch] * w3;
  #pragma unroll
  for (int k=1;k<=3;k++){
    float w = (k==1) ? w2 : (k==2) ? w1 : w0;
    if (tg >= k){
      int dtk = dt - k;
      int pp = (dtk >= 0) ? p : (p^1);
      int rr = b*64 + ((dtk + 64) & 63);
      acc += base[((size_t)pp*256 + rr)*2048 + ch] * w;
    }
  }
  xconvb[((size_t)l*256 + r)*DI + ch] = f2bf(siluf_(acc));
}

// ---- wavefront scan slot: 6 layers x 32 wgs x 512 thr; <=1 wg/CU ----
// R2-geometry restoration inside the wavefront: 192 wgs total (no CU sharing,
// no cross-layer issue-slot contention), 2x16B poll loads / 8 tags per thread
// (half of R13), s_sleep(1) fine-grain backoff, s_setprio(1) around the dot.
// Per-thread work identical to R13 (384 fdot2, 96 u32 weights, L2-remat).
// h protocol = proven per-dword {f16|u16 tag}, batch-interleaved [i][4b].
__global__ __launch_bounds__(512, 2) void scan_slot(
    int slot,
    const unsigned short* __restrict__ xihb,   // [NL][256][3072]
    const float* __restrict__ xz_ring,         // [NL][2][256][2048]
    const uint32_t* __restrict__ wT,           // thread-major packed f16, x4
    const float* __restrict__ bhh,             // [NL][3072]
    uint32_t* __restrict__ hbufs,              // [NL][2][1024][4] {f16|tag}
    unsigned short* __restrict__ xoutb)        // [NL][256][1024]
{
  const int w = blockIdx.x;
  const int l = w >> 5;
  const int g = w & 31;
  const int c = slot - l;
  if (c < 0 || c >= NCH) return;

  const int tid = threadIdx.x;
  const int il  = tid >> 4;          // 0..31
  const int ks  = tid & 15;          // 0..15 (64-wide h slice)
  const int i   = g*32 + il;

  const u32x4* pw4 = (const u32x4*)wT + ((size_t)(l*32 + g)*24)*512 + tid;

  const float* bh = bhh + l*3072;
  const float bhr = bh[i], bhz = bh[DI+i], bhn = bh[2*DI+i];

  __shared__ uint32_t hshw[2][NB][16*36];   // parity, batch plane, 16 rows x 36 u32

  const uint32_t lbase = (uint32_t)l << 10;
  uint32_t* hb = hbufs + (size_t)l*2*4096;
  const unsigned short* xih = xihb + (size_t)l*256*3072;
  const float* xzp = xz_ring + ((size_t)(l*2 + (c&1))*256)*2048;
  unsigned short* xo = xoutb + (size_t)l*256*DI;

  float xr_c[NB], xzg_c[NB], xn_c[NB], zg_c[NB];
  float xr_n[NB], xzg_n[NB], xn_n[NB], zg_n[NB];
  float hprev[NB] = {0.f,0.f,0.f,0.f};
  if (ks == 0){
    #pragma unroll
    for (int b4=0;b4<NB;b4++){
      int r = b4*64;
      xr_c[b4]  = bf2f(xih[(size_t)r*3072 + i]);
      xzg_c[b4] = bf2f(xih[(size_t)r*3072 + DI + i]);
      xn_c[b4]  = bf2f(xih[(size_t)r*3072 + 2*DI + i]);
      zg_c[b4]  = xzp[(size_t)r*2048 + DI + i];
    }
  }

  // thread polls slots for i1 = tid (rows 0..7) and i2 = tid+512 (rows 8..15)
  const int r1 = tid >> 6;           // 0..7
  const int c1 = tid & 63;           // u16 column

  for (int dt=0; dt<CHUNK; ++dt){
    const int t   = c*CHUNK + dt;
    const int par = t & 1;
    if (t == 0){
      uint32_t* hz = &hshw[0][0][0];
      for (int j=tid; j<NB*16*36; j+=512) hz[j] = 0u;
    } else {
      const uint32_t want = lbase + (uint32_t)t;
      const uintptr_t p = (uintptr_t)(hb + (size_t)par*4096 + 4*tid);
      u32x4 A0, A1;
      asm volatile("global_load_dwordx4 %0, %2, off sc1\n\t"
                   "global_load_dwordx4 %1, %3, off sc1\n\t"
                   "s_waitcnt vmcnt(0)"
                   : "=&v"(A0), "=&v"(A1)
                   : "v"(p), "v"(p + 8192));
      while (((A0[0]>>16)<want)|((A0[1]>>16)<want)|((A0[2]>>16)<want)|((A0[3]>>16)<want)|
             ((A1[0]>>16)<want)|((A1[1]>>16)<want)|((A1[2]>>16)<want)|((A1[3]>>16)<want)){
        __builtin_amdgcn_s_sleep(1);
        asm volatile("global_load_dwordx4 %0, %2, off sc1\n\t"
                     "global_load_dwordx4 %1, %3, off sc1\n\t"
                     "s_waitcnt vmcnt(0)"
                     : "=&v"(A0), "=&v"(A1)
                     : "v"(p), "v"(p + 8192));
      }
      uint16_t* hp16 = (uint16_t*)&hshw[par][0][0];   // plane stride 1152 u16
      #pragma unroll
      for (int b4=0;b4<NB;b4++){
        hp16[b4*1152 + r1*72 + c1]     = (uint16_t)A0[b4];
        hp16[b4*1152 + (r1+8)*72 + c1] = (uint16_t)A1[b4];
      }
    }
    __syncthreads();     // hshw[par] ready

    if (ks == 0 && dt == 0 && c > 0){
      const uint16_t* hp16 = (const uint16_t*)&hshw[par][0][0];
      #pragma unroll
      for (int b4=0;b4<NB;b4++){
        union { uint16_t u; _Float16 h; } hv;
        hv.u = hp16[b4*1152 + (i>>6)*72 + (i&63)];
        hprev[b4] = (float)hv.h;
      }
    }
    if (ks == 0 && dt+1 < CHUNK){
      #pragma unroll
      for (int b4=0;b4<NB;b4++){
        int r = b4*64 + dt + 1;
        xr_n[b4]  = bf2f(xih[(size_t)r*3072 + i]);
        xzg_n[b4] = bf2f(xih[(size_t)r*3072 + DI + i]);
        xn_n[b4]  = bf2f(xih[(size_t)r*3072 + 2*DI + i]);
        zg_n[b4]  = xzp[(size_t)r*2048 + DI + i];
      }
    }

    __builtin_amdgcn_s_setprio(1);
    float ar[NB] = {0,0,0,0}, az[NB] = {0,0,0,0}, an[NB] = {0,0,0,0};
    #pragma unroll
    for (int q=0;q<8;q++){
      u32x4 wrq = pw4[(size_t)q*512];
      u32x4 wzq = pw4[(size_t)(8+q)*512];
      u32x4 wnq = pw4[(size_t)(16+q)*512];
      #pragma unroll
      for (int b4=0;b4<NB;b4++){
        u32x4 hv = *(const u32x4*)&hshw[par][b4][ks*36 + 4*q];
        ar[b4] = __builtin_amdgcn_fdot2(u2h(wrq[0]), u2h(hv[0]), ar[b4], false);
        az[b4] = __builtin_amdgcn_fdot2(u2h(wzq[0]), u2h(hv[0]), az[b4], false);
        an[b4] = __builtin_amdgcn_fdot2(u2h(wnq[0]), u2h(hv[0]), an[b4], false);
        ar[b4] = __builtin_amdgcn_fdot2(u2h(wrq[1]), u2h(hv[1]), ar[b4], false);
        az[b4] = __builtin_amdgcn_fdot2(u2h(wzq[1]), u2h(hv[1]), az[b4], false);
        an[b4] = __builtin_amdgcn_fdot2(u2h(wnq[1]), u2h(hv[1]), an[b4], false);
        ar[b4] = __builtin_amdgcn_fdot2(u2h(wrq[2]), u2h(hv[2]), ar[b4], false);
        az[b4] = __builtin_amdgcn_fdot2(u2h(wzq[2]), u2h(hv[2]), az[b4], false);
        an[b4] = __builtin_amdgcn_fdot2(u2h(wnq[2]), u2h(hv[2]), an[b4], false);
        ar[b4] = __builtin_amdgcn_fdot2(u2h(wrq[3]), u2h(hv[3]), ar[b4], false);
        az[b4] = __builtin_amdgcn_fdot2(u2h(wzq[3]), u2h(hv[3]), az[b4], false);
        an[b4] = __builtin_amdgcn_fdot2(u2h(wnq[3]), u2h(hv[3]), an[b4], false);
      }
    }
    #pragma unroll
    for (int off=1; off<16; off<<=1){
      #pragma unroll
      for (int b4=0;b4<NB;b4++){
        ar[b4] += __shfl_xor(ar[b4], off);
        az[b4] += __shfl_xor(az[b4], off);
        an[b4] += __shfl_xor(an[b4], off);
      }
    }
    __builtin_amdgcn_s_setprio(0);

    if (ks == 0){
      u32x4 HW;
      const uint32_t ntag = (lbase + (uint32_t)t + 1u) << 16;
      #pragma unroll
      for (int b4=0;b4<NB;b4++){
        float r_ = sigmoidf_(xr_c[b4] + ar[b4] + bhr);
        float z_ = sigmoidf_(xzg_c[b4] + az[b4] + bhz);
        float n_ = tanhf_(xn_c[b4] + r_*(an[b4] + bhn));
        float hnew = (1.f - z_)*n_ + z_*hprev[b4];
        hprev[b4] = hnew;
        HW[b4] = (pkrtz2u(hnew, 0.f) & 0xffffu) | ntag;
        int r = b4*64 + dt;
        xo[(size_t)r*DI + i] = f2bf(hnew * siluf_(zg_c[b4]));
        xr_c[b4]=xr_n[b4]; xzg_c[b4]=xzg_n[b4]; xn_c[b4]=xn_n[b4]; zg_c[b4]=zg_n[b4];
      }
      const uintptr_t hdst = (uintptr_t)(hb + (size_t)((t+1)&1)*4096 + 4*i);
      asm volatile("global_store_dwordx4 %0, %1, off sc1"
                   :: "v"(hdst), "v"(HW));
    }
  }
}

// ---------------- host ----------------
extern "C" void kernel_launch(void* const* d_in, const int* in_sizes, int n_in,
                              void* d_out, int out_size, void* d_ws, size_t ws_size,
                              hipStream_t stream)
{
  (void)in_sizes; (void)n_in; (void)out_size; (void)ws_size;
  const float* x      = (const float*)d_in[0];
  const float* norm_w = (const float*)d_in[1];
  const float* norm_b = (const float*)d_in[2];
  const float* inw    = (const float*)d_in[3];
  const float* inb    = (const float*)d_in[4];
  const float* convw  = (const float*)d_in[5];
  const float* convb  = (const float*)d_in[6];
  const float* wih    = (const float*)d_in[7];
  const float* whh    = (const float*)d_in[8];
  const float* bih    = (const float*)d_in[9];
  const float* bhh    = (const float*)d_in[10];
  const float* outw   = (const float*)d_in[11];
  const float* outb   = (const float*)d_in[12];
  const float* normfw = (const float*)d_in[13];
  const float* normfb = (const float*)d_in[14];
  float* out = (float*)d_out;

  char* ws = (char*)d_ws;
  size_t off = 0;
  auto alloc = [&](size_t bytes)->void*{ void* p = ws + off; off = (off + bytes + 255) & ~(size_t)255; return p; };
  uint32_t*       wT      = (uint32_t*)      alloc((size_t)NL*32*24*512*16);
  unsigned short* lnbf    = (unsigned short*)alloc((size_t)NL*256*DM*2);
  float*          xz_ring = (float*)         alloc((size_t)NL*2*256*2048*4);
  unsigned short* xconvb  = (unsigned short*)alloc((size_t)NL*256*DI*2);
  unsigned short* xihb    = (unsigned short*)alloc((size_t)NL*256*3072*2);
  unsigned short* xoutb   = (unsigned short*)alloc((size_t)NL*256*DI*2);
  float*          resid_ring  = (float*)     alloc((size_t)NL*2*256*DM*4);
  float*          hidden_ring = (float*)     alloc((size_t)NL*2*256*DM*4);
  float*          resid5  = (float*)         alloc((size_t)BT*DM*4);
  float*          hidden5 = (float*)         alloc((size_t)BT*DM*4);
  uint32_t*       hbufs   = (uint32_t*)      alloc((size_t)NL*2*4096*4);

  hipMemsetAsync(hbufs, 0, (size_t)NL*2*4096*4, stream);
  cvtwt_kernel<<<2048, 256, 0, stream>>>(whh, wT);

  for (int slot = 0; slot < NSLOT; ++slot){
    lnres_slot<<<dim3(64,1,NL), 256, 0, stream>>>(slot, x, norm_w, norm_b,
                                                  hidden_ring, resid_ring, resid5, lnbf);
    gemm_slot<<<dim3(16,2,NL), 256, 0, stream>>>(0, slot, lnbf, inw, inb, xz_ring,
                                                 xconvb, wih, bih, xihb,
                                                 xoutb, outw, outb, hidden_ring, hidden5);
    conv_slot<<<dim3(1024,1,NL), 256, 0, stream>>>(slot, xz_ring, convw, convb, xconvb);
    gemm_slot<<<dim3(24,2,NL), 256, 0, stream>>>(1, slot, lnbf, inw, inb, xz_ring,
                                                 xconvb, wih, bih, xihb,
                                                 xoutb, outw, outb, hidden_ring, hidden5);
    scan_slot<<<dim3(NL*32), 512, 0, stream>>>(slot, xihb, xz_ring, wT, bhh, hbufs, xoutb);
    gemm_slot<<<dim3(4,2,NL), 256, 0, stream>>>(2, slot, lnbf, inw, inb, xz_ring,
                                                xconvb, wih, bih, xihb,
                                                xoutb, outw, outb, hidden_ring, hidden5);
  }
  ln_final<<<1024, 256, 0, stream>>>(hidden5, resid5, normfw, normfb, out);
}

// Round 17
// 10146.069 us; speedup vs baseline: 1.3016x; 1.3016x over previous
//
#include <hip/hip_runtime.h>
#include <hip/hip_bf16.h>
#include <stdint.h>

#define SEQ   1024
#define NB    4
#define BT    4096
#define DM    512
#define DI    1024
#define NL    6
#define CHUNK 64
#define NCH   16          // SEQ/CHUNK
#define NSLOT (NL + NCH - 1)

typedef float  f32x4  __attribute__((ext_vector_type(4)));
typedef short  bf16x8 __attribute__((ext_vector_type(8)));
typedef _Float16 f16x2 __attribute__((ext_vector_type(2)));
typedef uint32_t u32x4 __attribute__((ext_vector_type(4)));

__device__ __forceinline__ float bf2f(unsigned short u){
  union { unsigned int i; float f; } v; v.i = ((unsigned int)u) << 16; return v.f;
}
__device__ __forceinline__ unsigned short f2bf(float f){
  union { float f; unsigned int i; } v; v.f = f;
  unsigned int x = v.i;
  return (unsigned short)((x + 0x7fffu + ((x >> 16) & 1u)) >> 16);
}
__device__ __forceinline__ float bits2f(uint32_t u){
  union { uint32_t i; float f; } v; v.i = u; return v.f;
}
__device__ __forceinline__ f16x2 u2h(uint32_t u){
  union { uint32_t u; f16x2 h; } v; v.u = u; return v.h;
}
__device__ __forceinline__ uint32_t pkrtz2u(float a, float b){
  union { __fp16 __attribute__((ext_vector_type(2))) h; uint32_t u; } v;
  v.h = __builtin_amdgcn_cvt_pkrtz(a, b);
  return v.u;
}
__device__ __forceinline__ uint32_t packf16(float a, float b){
  union { _Float16 h[2]; uint32_t u; } v;
  v.h[0] = (_Float16)a; v.h[1] = (_Float16)b; return v.u;
}
__device__ __forceinline__ float sigmoidf_(float x){ return __fdividef(1.f, 1.f + __expf(-x)); }
__device__ __forceinline__ float siluf_(float x){ return x * __fdividef(1.f, 1.f + __expf(-x)); }
__device__ __forceinline__ float tanhf_(float x){
  float e = __expf(2.f*x);
  return 1.f - __fdividef(2.f, e + 1.f);
}

// ---- whh f32 -> thread-major packed f16 (R13 layout: 96 words x 256 thr) ----
__global__ __launch_bounds__(256) void cvtwt_kernel(const float* __restrict__ whh,
                                                    uint32_t* __restrict__ wT){
  const int n = NL*64*96*256;
  for (int idx = blockIdx.x*256 + threadIdx.x; idx < n; idx += gridDim.x*256){
    int tid = idx & 255;
    int rest = idx >> 8;
    int j = rest % 96;
    int rest2 = rest / 96;
    int g = rest2 & 63;
    int l = rest2 >> 6;
    int il = tid >> 4, ks = tid & 15;
    int i = g*16 + il;
    int G = j >> 5, jj = j & 31;
    int k = ks*64 + 2*jj;
    const float* src = whh + ((size_t)l*3072 + G*1024 + i)*1024 + k;
    wT[idx] = packf16(src[0], src[1]);
  }
}

// ---- per-slot fused residual+LN ----
__global__ __launch_bounds__(256) void lnres_slot(
    int slot, const float* __restrict__ x,
    const float* __restrict__ norm_w, const float* __restrict__ norm_b,
    float* __restrict__ hidden_ring,   // [NL][2][256][512]
    float* __restrict__ resid_ring,    // [NL][2][256][512]
    float* __restrict__ resid5,        // [4096][512]
    unsigned short* __restrict__ lnbf) // [NL][256][512]
{
  const int l = blockIdx.z, c = slot - l;
  if (c < 0 || c >= NCH) return;
  const int wave = threadIdx.x >> 6;
  const int lane = threadIdx.x & 63;
  const int r = blockIdx.x*4 + wave;
  const int b = r >> 6, dt = r & 63;
  const int tg = c*CHUNK + dt;
  const int p = c & 1;

  const float* hid = (l == 0) ? x + ((size_t)b*SEQ + tg)*DM + lane*8
                              : hidden_ring + (((size_t)(l-1)*2 + p)*256 + r)*DM + lane*8;
  float4 a0 = *(const float4*)hid;
  float4 a1 = *(const float4*)(hid + 4);
  if (l > 0){
    const float* rin = resid_ring + (((size_t)(l-1)*2 + p)*256 + r)*DM + lane*8;
    float4 b0 = *(const float4*)rin;
    float4 b1 = *(const float4*)(rin + 4);
    a0.x+=b0.x; a0.y+=b0.y; a0.z+=b0.z; a0.w+=b0.w;
    a1.x+=b1.x; a1.y+=b1.y; a1.z+=b1.z; a1.w+=b1.w;
  }
  float* rout = (l == 5) ? resid5 + ((size_t)b*SEQ + tg)*DM + lane*8
                         : resid_ring + (((size_t)l*2 + p)*256 + r)*DM + lane*8;
  *(float4*)rout = a0;
  *(float4*)(rout + 4) = a1;

  float xv[8] = {a0.x,a0.y,a0.z,a0.w,a1.x,a1.y,a1.z,a1.w};
  float s = 0.f, sq = 0.f;
  #pragma unroll
  for (int q=0;q<8;q++){ s += xv[q]; sq += xv[q]*xv[q]; }
  #pragma unroll
  for (int off=32; off; off>>=1){ s += __shfl_xor(s, off); sq += __shfl_xor(sq, off); }
  float mean = s * (1.f/DM);
  float var  = sq * (1.f/DM) - mean*mean;
  float rstd = rsqrtf(var + 1e-5f);
  const float* gamma = norm_w + l*DM;
  const float* beta  = norm_b + l*DM;
  float4 g0 = *(const float4*)(gamma + lane*8);
  float4 g1 = *(const float4*)(gamma + lane*8 + 4);
  float4 e0 = *(const float4*)(beta  + lane*8);
  float4 e1 = *(const float4*)(beta  + lane*8 + 4);
  float gv[8] = {g0.x,g0.y,g0.z,g0.w,g1.x,g1.y,g1.z,g1.w};
  float ev[8] = {e0.x,e0.y,e0.z,e0.w,e1.x,e1.y,e1.z,e1.w};
  uint4 pk;
  float y0 = (xv[0]-mean)*rstd*gv[0]+ev[0], y1 = (xv[1]-mean)*rstd*gv[1]+ev[1];
  float y2 = (xv[2]-mean)*rstd*gv[2]+ev[2], y3 = (xv[3]-mean)*rstd*gv[3]+ev[3];
  float y4 = (xv[4]-mean)*rstd*gv[4]+ev[4], y5 = (xv[5]-mean)*rstd*gv[5]+ev[5];
  float y6 = (xv[6]-mean)*rstd*gv[6]+ev[6], y7 = (xv[7]-mean)*rstd*gv[7]+ev[7];
  pk.x = (unsigned)f2bf(y0) | ((unsigned)f2bf(y1)<<16);
  pk.y = (unsigned)f2bf(y2) | ((unsigned)f2bf(y3)<<16);
  pk.z = (unsigned)f2bf(y4) | ((unsigned)f2bf(y5)<<16);
  pk.w = (unsigned)f2bf(y6) | ((unsigned)f2bf(y7)<<16);
  *(uint4*)(lnbf + ((size_t)l*256 + r)*DM + lane*8) = pk;
}

// ---- final layernorm (full 4096 rows) ----
__global__ __launch_bounds__(256) void ln_final(
    const float* __restrict__ hidden, const float* __restrict__ resid_in,
    const float* __restrict__ gamma,  const float* __restrict__ beta,
    float* __restrict__ out_f32)
{
  int wave = threadIdx.x >> 6;
  int lane = threadIdx.x & 63;
  int row  = blockIdx.x*4 + wave;
  size_t base = (size_t)row * DM + lane*8;
  float4 a0 = *(const float4*)(hidden + base);
  float4 a1 = *(const float4*)(hidden + base + 4);
  float4 b0 = *(const float4*)(resid_in + base);
  float4 b1 = *(const float4*)(resid_in + base + 4);
  a0.x+=b0.x; a0.y+=b0.y; a0.z+=b0.z; a0.w+=b0.w;
  a1.x+=b1.x; a1.y+=b1.y; a1.z+=b1.z; a1.w+=b1.w;
  float xv[8] = {a0.x,a0.y,a0.z,a0.w,a1.x,a1.y,a1.z,a1.w};
  float s = 0.f, sq = 0.f;
  #pragma unroll
  for (int q=0;q<8;q++){ s += xv[q]; sq += xv[q]*xv[q]; }
  #pragma unroll
  for (int off=32; off; off>>=1){ s += __shfl_xor(s, off); sq += __shfl_xor(sq, off); }
  float mean = s * (1.f/DM);
  float var  = sq * (1.f/DM) - mean*mean;
  float rstd = rsqrtf(var + 1e-5f);
  float4 g0 = *(const float4*)(gamma + lane*8);
  float4 g1 = *(const float4*)(gamma + lane*8 + 4);
  float4 e0 = *(const float4*)(beta  + lane*8);
  float4 e1 = *(const float4*)(beta  + lane*8 + 4);
  float gv[8] = {g0.x,g0.y,g0.z,g0.w,g1.x,g1.y,g1.z,g1.w};
  float ev[8] = {e0.x,e0.y,e0.z,e0.w,e1.x,e1.y,e1.z,e1.w};
  float4 o0, o1;
  o0.x=(xv[0]-mean)*rstd*gv[0]+ev[0]; o0.y=(xv[1]-mean)*rstd*gv[1]+ev[1];
  o0.z=(xv[2]-mean)*rstd*gv[2]+ev[2]; o0.w=(xv[3]-mean)*rstd*gv[3]+ev[3];
  o1.x=(xv[4]-mean)*rstd*gv[4]+ev[4]; o1.y=(xv[5]-mean)*rstd*gv[5]+ev[5];
  o1.z=(xv[6]-mean)*rstd*gv[6]+ev[6]; o1.w=(xv[7]-mean)*rstd*gv[7]+ev[7];
  *(float4*)(out_f32 + base)     = o0;
  *(float4*)(out_f32 + base + 4) = o1;
}

// ---- per-slot GEMM, A bf16 x B f32(on-the-fly->bf16)^T, M=256 ----
__device__ __forceinline__ bf16x8 ldcvt8(const float* p){
  float4 u = *(const float4*)p;
  float4 v = *(const float4*)(p + 4);
  bf16x8 r;
  r[0]=(short)f2bf(u.x); r[1]=(short)f2bf(u.y); r[2]=(short)f2bf(u.z); r[3]=(short)f2bf(u.w);
  r[4]=(short)f2bf(v.x); r[5]=(short)f2bf(v.y); r[6]=(short)f2bf(v.z); r[7]=(short)f2bf(v.w);
  return r;
}
__global__ __launch_bounds__(256) void gemm_slot(
    int op, int slot,
    const unsigned short* __restrict__ lnbf, const float* __restrict__ inw,
    const float* __restrict__ inb, float* __restrict__ xz_ring,
    const unsigned short* __restrict__ xconvb, const float* __restrict__ wih,
    const float* __restrict__ bih, unsigned short* __restrict__ xihb,
    const unsigned short* __restrict__ xoutb, const float* __restrict__ outw,
    const float* __restrict__ outb, float* __restrict__ hidden_ring,
    float* __restrict__ hidden5)
{
  const int l = blockIdx.z, c = slot - l;
  if (c < 0 || c >= NCH) return;

  const unsigned short* A; const float* Bf; const float* bias;
  int N, K;
  if (op == 0){ A = lnbf   + (size_t)l*256*DM;  Bf = inw  + (size_t)l*2048*512;  bias = inb  + l*2048; N = 2048; K = 512; }
  else if (op == 1){ A = xconvb + (size_t)l*256*DI; Bf = wih  + (size_t)l*3072*1024; bias = bih  + l*3072; N = 3072; K = 1024; }
  else { A = xoutb  + (size_t)l*256*DI; Bf = outw + (size_t)l*512*1024;  bias = outb + l*512;  N = 512;  K = 1024; }

  const int tid  = threadIdx.x;
  const int wid  = tid >> 6, lane = tid & 63;
  const int wm   = wid >> 1, wn = wid & 1;
  const int tm   = blockIdx.y*128 + wm*64;
  const int tn   = blockIdx.x*128 + wn*64;
  const int l15  = lane & 15;
  const int lk   = (lane >> 4) * 8;

  f32x4 acc[4][4] = {};
  for (int kk = 0; kk < K; kk += 32){
    bf16x8 a[4], b[4];
    #pragma unroll
    for (int f=0; f<4; ++f)
      a[f] = *(const bf16x8*)(A + (size_t)(tm + f*16 + l15)*K + kk + lk);
    #pragma unroll
    for (int f=0; f<4; ++f)
      b[f] = ldcvt8(Bf + (size_t)(tn + f*16 + l15)*K + kk + lk);
    #pragma unroll
    for (int i=0;i<4;i++)
      #pragma unroll
      for (int j=0;j<4;j++)
        acc[i][j] = __builtin_amdgcn_mfma_f32_16x16x32_bf16(a[i], b[j], acc[i][j], 0,0,0);
  }
  const int crow0 = (lane>>4)*4;
  const int p = c & 1;
  #pragma unroll
  for (int i=0;i<4;i++){
    #pragma unroll
    for (int j=0;j<4;j++){
      int col = tn + j*16 + l15;
      float bv = bias[col];
      #pragma unroll
      for (int r=0;r<4;r++){
        int row = tm + i*16 + crow0 + r;
        float val = acc[i][j][r] + bv;
        if (op == 0){
          xz_ring[(((size_t)l*2 + p)*256 + row)*2048 + col] = val;
        } else if (op == 1){
          xihb[((size_t)l*256 + row)*3072 + col] = f2bf(val);
        } else {
          if (l == 5){
            int b_ = row >> 6, dt = row & 63;
            hidden5[((size_t)b_*SEQ + c*CHUNK + dt)*DM + col] = val;
          } else {
            hidden_ring[(((size_t)l*2 + p)*256 + row)*DM + col] = val;
          }
        }
      }
    }
  }
}

// ---- per-slot causal conv(4)+SiLU, 8-wide vectorized ----
// thread handles 8 channels of one row; 128 wgs/layer.
__global__ __launch_bounds__(256) void conv_slot(
    int slot, const float* __restrict__ xz_ring,
    const float* __restrict__ cw, const float* __restrict__ cb,
    unsigned short* __restrict__ xconvb)
{
  const int l = blockIdx.z, c = slot - l;
  if (c < 0 || c >= NCH) return;
  const int idx = blockIdx.x*256 + threadIdx.x;   // 0..32767
  const int ch0 = (idx & 127) * 8;
  const int r   = idx >> 7;                       // 0..255
  const int b   = r >> 6, dt = r & 63;
  const int tg  = c*CHUNK + dt;
  const int p   = c & 1;

  const float* base = xz_ring + ((size_t)l*2)*256*2048;
  float xt[4][8];
  { const float* pr = base + ((size_t)p*256 + r)*2048 + ch0;
    *(float4*)&xt[0][0] = *(const float4*)pr;
    *(float4*)&xt[0][4] = *(const float4*)(pr + 4); }
  #pragma unroll
  for (int k=1;k<=3;k++){
    if (tg >= k){
      int dtk = dt - k;
      int pp = (dtk >= 0) ? p : (p^1);
      int rr = b*64 + ((dtk + 64) & 63);
      const float* pr = base + ((size_t)pp*256 + rr)*2048 + ch0;
      *(float4*)&xt[k][0] = *(const float4*)pr;
      *(float4*)&xt[k][4] = *(const float4*)(pr + 4);
    } else {
      #pragma unroll
      for (int j=0;j<8;j++) xt[k][j] = 0.f;
    }
  }
  const float* cbp = cb + l*DI + ch0;
  float cbv[8];
  *(float4*)&cbv[0] = *(const float4*)cbp;
  *(float4*)&cbv[4] = *(const float4*)(cbp + 4);

  unsigned short ov[8];
  #pragma unroll
  for (int j=0;j<8;j++){
    float4 wv = *(const float4*)(cw + ((size_t)(l*DI + ch0 + j))*4);
    float acc = cbv[j] + xt[0][j]*wv.w + xt[1][j]*wv.z + xt[2][j]*wv.y + xt[3][j]*wv.x;
    ov[j] = f2bf(siluf_(acc));
  }
  uint4 pk;
  pk.x = (unsigned)ov[0] | ((unsigned)ov[1]<<16);
  pk.y = (unsigned)ov[2] | ((unsigned)ov[3]<<16);
  pk.z = (unsigned)ov[4] | ((unsigned)ov[5]<<16);
  pk.w = (unsigned)ov[6] | ((unsigned)ov[7]<<16);
  *(uint4*)(xconvb + ((size_t)l*256 + r)*DI + ch0) = pk;
}

// ---- wavefront scan slot: 6 layers x 64 wgs x 256 thr; 4 batches/wg ----
// R13 geometry (proven 416us) + PARALLEL GATES: lanes ks=0..3 each own batch
// b4=ks (scalar gate math, own h-dword store, own xout store, own x-prefetch)
// -> removes the single-lane serial 4-batch gate chain.
// h protocol = proven per-dword {f16|u16 tag}, batch-interleaved [i][4b].
__global__ __launch_bounds__(256, 2) void scan_slot(
    int slot,
    const unsigned short* __restrict__ xihb,   // [NL][256][3072]
    const float* __restrict__ xz_ring,         // [NL][2][256][2048]
    const uint32_t* __restrict__ wT,           // thread-major packed f16
    const float* __restrict__ bhh,             // [NL][3072]
    uint32_t* __restrict__ hbufs,              // [NL][2][1024][4] {f16|tag}
    unsigned short* __restrict__ xoutb)        // [NL][256][1024]
{
  const int w = blockIdx.x;
  const int l = w >> 6;
  const int g = w & 63;
  const int c = slot - l;
  if (c < 0 || c >= NCH) return;

  const int tid = threadIdx.x;
  const int il  = tid >> 4;          // 0..15
  const int ks  = tid & 15;          // 0..15 (64-wide h slice)
  const int i   = g*16 + il;

  const uint32_t* pw = wT + ((size_t)(l*64 + g)*96)*256 + tid;
  uint32_t wrp[32], wzp[32], wnp[32];
  #pragma unroll
  for (int j=0;j<32;j++) wrp[j] = pw[(size_t)j*256];
  #pragma unroll
  for (int j=0;j<32;j++) wzp[j] = pw[(size_t)(32+j)*256];
  #pragma unroll
  for (int j=0;j<32;j++) wnp[j] = pw[(size_t)(64+j)*256];

  const float* bh = bhh + l*3072;
  const float bhr = bh[i], bhz = bh[DI+i], bhn = bh[2*DI+i];

  __shared__ uint32_t hshw[2][NB][16*36];   // parity, batch plane, 16 rows x 36 u32

  const uint32_t lbase = (uint32_t)l << 10;
  uint32_t* hb = hbufs + (size_t)l*2*4096;
  const unsigned short* xih = xihb + (size_t)l*256*3072;
  const float* xzp = xz_ring + ((size_t)(l*2 + (c&1))*256)*2048;
  unsigned short* xo = xoutb + (size_t)l*256*DI;

  // lane ks<4 owns batch ks: scalar x regs + scalar hprev
  float xr_c=0.f, xzg_c=0.f, xn_c=0.f, zg_c=0.f;
  float xr_n=0.f, xzg_n=0.f, xn_n=0.f, zg_n=0.f;
  float hprev = 0.f;
  if (ks < 4){
    int r = ks*64;
    xr_c  = bf2f(xih[(size_t)r*3072 + i]);
    xzg_c = bf2f(xih[(size_t)r*3072 + DI + i]);
    xn_c  = bf2f(xih[(size_t)r*3072 + 2*DI + i]);
    zg_c  = xzp[(size_t)r*2048 + DI + i];
  }

  const int r0 = tid >> 6;         // base LDS row of this thread's polled i's
  const int c0 = tid & 63;         // u16 column

  for (int dt=0; dt<CHUNK; ++dt){
    const int t   = c*CHUNK + dt;
    const int par = t & 1;
    if (t == 0){
      uint32_t* hz = &hshw[0][0][0];
      for (int j=tid; j<NB*16*36; j+=256) hz[j] = 0u;
    } else {
      const uint32_t want = lbase + (uint32_t)t;
      const uintptr_t p = (uintptr_t)(hb + (size_t)par*4096 + 4*tid);
      u32x4 A0, A1, A2, A3;
      asm volatile("global_load_dwordx4 %0, %4, off sc1\n\t"
                   "global_load_dwordx4 %1, %5, off sc1\n\t"
                   "global_load_dwordx4 %2, %6, off sc1\n\t"
                   "global_load_dwordx4 %3, %7, off sc1\n\t"
                   "s_waitcnt vmcnt(0)"
                   : "=&v"(A0), "=&v"(A1), "=&v"(A2), "=&v"(A3)
                   : "v"(p), "v"(p+4096), "v"(p+8192), "v"(p+12288));
      while (((A0[0]>>16)<want)|((A0[1]>>16)<want)|((A0[2]>>16)<want)|((A0[3]>>16)<want)|
             ((A1[0]>>16)<want)|((A1[1]>>16)<want)|((A1[2]>>16)<want)|((A1[3]>>16)<want)|
             ((A2[0]>>16)<want)|((A2[1]>>16)<want)|((A2[2]>>16)<want)|((A2[3]>>16)<want)|
             ((A3[0]>>16)<want)|((A3[1]>>16)<want)|((A3[2]>>16)<want)|((A3[3]>>16)<want)){
        __builtin_amdgcn_s_sleep(8);
        asm volatile("global_load_dwordx4 %0, %4, off sc1\n\t"
                     "global_load_dwordx4 %1, %5, off sc1\n\t"
                     "global_load_dwordx4 %2, %6, off sc1\n\t"
                     "global_load_dwordx4 %3, %7, off sc1\n\t"
                     "s_waitcnt vmcnt(0)"
                     : "=&v"(A0), "=&v"(A1), "=&v"(A2), "=&v"(A3)
                     : "v"(p), "v"(p+4096), "v"(p+8192), "v"(p+12288));
      }
      uint16_t* hp16 = (uint16_t*)&hshw[par][0][0];   // plane stride 1152 u16
      #pragma unroll
      for (int b4=0;b4<NB;b4++){
        hp16[b4*1152 + (r0+ 0)*72 + c0] = (uint16_t)A0[b4];
        hp16[b4*1152 + (r0+ 4)*72 + c0] = (uint16_t)A1[b4];
        hp16[b4*1152 + (r0+ 8)*72 + c0] = (uint16_t)A2[b4];
        hp16[b4*1152 + (r0+12)*72 + c0] = (uint16_t)A3[b4];
      }
    }
    __syncthreads();     // hshw[par] ready

    if (ks < 4 && dt == 0 && c > 0){
      const uint16_t* hp16 = (const uint16_t*)&hshw[par][0][0];
      union { uint16_t u; _Float16 h; } hv;
      hv.u = hp16[ks*1152 + (i>>6)*72 + (i&63)];
      hprev = (float)hv.h;
    }
    if (ks < 4 && dt+1 < CHUNK){
      int r = ks*64 + dt + 1;
      xr_n  = bf2f(xih[(size_t)r*3072 + i]);
      xzg_n = bf2f(xih[(size_t)r*3072 + DI + i]);
      xn_n  = bf2f(xih[(size_t)r*3072 + 2*DI + i]);
      zg_n  = xzp[(size_t)r*2048 + DI + i];
    }

    float ar[NB] = {0,0,0,0}, az[NB] = {0,0,0,0}, an[NB] = {0,0,0,0};
    #pragma unroll
    for (int q=0;q<8;q++){
      #pragma unroll
      for (int b4=0;b4<NB;b4++){
        u32x4 hv = *(const u32x4*)&hshw[par][b4][ks*36 + 4*q];
        ar[b4] = __builtin_amdgcn_fdot2(u2h(wrp[4*q+0]), u2h(hv[0]), ar[b4], false);
        az[b4] = __builtin_amdgcn_fdot2(u2h(wzp[4*q+0]), u2h(hv[0]), az[b4], false);
        an[b4] = __builtin_amdgcn_fdot2(u2h(wnp[4*q+0]), u2h(hv[0]), an[b4], false);
        ar[b4] = __builtin_amdgcn_fdot2(u2h(wrp[4*q+1]), u2h(hv[1]), ar[b4], false);
        az[b4] = __builtin_amdgcn_fdot2(u2h(wzp[4*q+1]), u2h(hv[1]), az[b4], false);
        an[b4] = __builtin_amdgcn_fdot2(u2h(wnp[4*q+1]), u2h(hv[1]), an[b4], false);
        ar[b4] = __builtin_amdgcn_fdot2(u2h(wrp[4*q+2]), u2h(hv[2]), ar[b4], false);
        az[b4] = __builtin_amdgcn_fdot2(u2h(wzp[4*q+2]), u2h(hv[2]), az[b4], false);
        an[b4] = __builtin_amdgcn_fdot2(u2h(wnp[4*q+2]), u2h(hv[2]), an[b4], false);
        ar[b4] = __builtin_amdgcn_fdot2(u2h(wrp[4*q+3]), u2h(hv[3]), ar[b4], false);
        az[b4] = __builtin_amdgcn_fdot2(u2h(wzp[4*q+3]), u2h(hv[3]), az[b4], false);
        an[b4] = __builtin_amdgcn_fdot2(u2h(wnp[4*q+3]), u2h(hv[3]), an[b4], false);
      }
    }
    #pragma unroll
    for (int off=1; off<16; off<<=1){
      #pragma unroll
      for (int b4=0;b4<NB;b4++){
        ar[b4] += __shfl_xor(ar[b4], off);
        az[b4] += __shfl_xor(az[b4], off);
        an[b4] += __shfl_xor(an[b4], off);
      }
    }

    if (ks < 4){
      const int b4 = ks;
      float r_ = sigmoidf_(xr_c + ar[b4] + bhr);
      float z_ = sigmoidf_(xzg_c + az[b4] + bhz);
      float n_ = tanhf_(xn_c + r_*(an[b4] + bhn));
      float hnew = (1.f - z_)*n_ + z_*hprev;
      hprev = hnew;
      uint32_t hw = (pkrtz2u(hnew, 0.f) & 0xffffu)
                  | ((lbase + (uint32_t)t + 1u) << 16);
      const uintptr_t hdst = (uintptr_t)(hb + (size_t)((t+1)&1)*4096 + 4*i + b4);
      asm volatile("global_store_dword %0, %1, off sc1"
                   :: "v"(hdst), "v"(hw));
      int r = b4*64 + dt;
      xo[(size_t)r*DI + i] = f2bf(hnew * siluf_(zg_c));
      xr_c = xr_n; xzg_c = xzg_n; xn_c = xn_n; zg_c = zg_n;
    }
  }
}

// ---------------- host ----------------
extern "C" void kernel_launch(void* const* d_in, const int* in_sizes, int n_in,
                              void* d_out, int out_size, void* d_ws, size_t ws_size,
                              hipStream_t stream)
{
  (void)in_sizes; (void)n_in; (void)out_size; (void)ws_size;
  const float* x      = (const float*)d_in[0];
  const float* norm_w = (const float*)d_in[1];
  const float* norm_b = (const float*)d_in[2];
  const float* inw    = (const float*)d_in[3];
  const float* inb    = (const float*)d_in[4];
  const float* convw  = (const float*)d_in[5];
  const float* convb  = (const float*)d_in[6];
  const float* wih    = (const float*)d_in[7];
  const float* whh    = (const float*)d_in[8];
  const float* bih    = (const float*)d_in[9];
  const float* bhh    = (const float*)d_in[10];
  const float* outw   = (const float*)d_in[11];
  const float* outb   = (const float*)d_in[12];
  const float* normfw = (const float*)d_in[13];
  const float* normfb = (const float*)d_in[14];
  float* out = (float*)d_out;

  char* ws = (char*)d_ws;
  size_t off = 0;
  auto alloc = [&](size_t bytes)->void*{ void* p = ws + off; off = (off + bytes + 255) & ~(size_t)255; return p; };
  uint32_t*       wT      = (uint32_t*)      alloc((size_t)NL*64*96*256*4);
  unsigned short* lnbf    = (unsigned short*)alloc((size_t)NL*256*DM*2);
  float*          xz_ring = (float*)         alloc((size_t)NL*2*256*2048*4);
  unsigned short* xconvb  = (unsigned short*)alloc((size_t)NL*256*DI*2);
  unsigned short* xihb    = (unsigned short*)alloc((size_t)NL*256*3072*2);
  unsigned short* xoutb   = (unsigned short*)alloc((size_t)NL*256*DI*2);
  float*          resid_ring  = (float*)     alloc((size_t)NL*2*256*DM*4);
  float*          hidden_ring = (float*)     alloc((size_t)NL*2*256*DM*4);
  float*          resid5  = (float*)         alloc((size_t)BT*DM*4);
  float*          hidden5 = (float*)         alloc((size_t)BT*DM*4);
  uint32_t*       hbufs   = (uint32_t*)      alloc((size_t)NL*2*4096*4);

  hipMemsetAsync(hbufs, 0, (size_t)NL*2*4096*4, stream);
  cvtwt_kernel<<<2048, 256, 0, stream>>>(whh, wT);

  for (int slot = 0; slot < NSLOT; ++slot){
    lnres_slot<<<dim3(64,1,NL), 256, 0, stream>>>(slot, x, norm_w, norm_b,
                                                  hidden_ring, resid_ring, resid5, lnbf);
    gemm_slot<<<dim3(16,2,NL), 256, 0, stream>>>(0, slot, lnbf, inw, inb, xz_ring,
                                                 xconvb, wih, bih, xihb,
                                                 xoutb, outw, outb, hidden_ring, hidden5);
    conv_slot<<<dim3(128,1,NL), 256, 0, stream>>>(slot, xz_ring, convw, convb, xconvb);
    gemm_slot<<<dim3(24,2,NL), 256, 0, stream>>>(1, slot, lnbf, inw, inb, xz_ring,
                                                 xconvb, wih, bih, xihb,
                                                 xoutb, outw, outb, hidden_ring, hidden5);
    scan_slot<<<dim3(NL*64), 256, 0, stream>>>(slot, xihb, xz_ring, wT, bhh, hbufs, xoutb);
    gemm_slot<<<dim3(4,2,NL), 256, 0, stream>>>(2, slot, lnbf, inw, inb, xz_ring,
                                                xconvb, wih, bih, xihb,
                                                xoutb, outw, outb, hidden_ring, hidden5);
  }
  ln_final<<<1024, 256, 0, stream>>>(hidden5, resid5, normfw, normfb, out);
}

// Round 18
// 9968.819 us; speedup vs baseline: 1.3248x; 1.0178x over previous
//
#include <hip/hip_runtime.h>
#include <hip/hip_bf16.h>
#include <stdint.h>

#define SEQ   1024
#define NB    4
#define BT    4096
#define DM    512
#define DI    1024
#define NL    6
#define CHUNK 64
#define NCH   16          // SEQ/CHUNK
#define NSLOT (NL + NCH - 1)

typedef float  f32x4  __attribute__((ext_vector_type(4)));
typedef short  bf16x8 __attribute__((ext_vector_type(8)));
typedef _Float16 f16x2 __attribute__((ext_vector_type(2)));
typedef uint32_t u32x4 __attribute__((ext_vector_type(4)));

__device__ __forceinline__ float bf2f(unsigned short u){
  union { unsigned int i; float f; } v; v.i = ((unsigned int)u) << 16; return v.f;
}
__device__ __forceinline__ unsigned short f2bf(float f){
  union { float f; unsigned int i; } v; v.f = f;
  unsigned int x = v.i;
  return (unsigned short)((x + 0x7fffu + ((x >> 16) & 1u)) >> 16);
}
__device__ __forceinline__ float bits2f(uint32_t u){
  union { uint32_t i; float f; } v; v.i = u; return v.f;
}
__device__ __forceinline__ f16x2 u2h(uint32_t u){
  union { uint32_t u; f16x2 h; } v; v.u = u; return v.h;
}
__device__ __forceinline__ uint32_t pkrtz2u(float a, float b){
  union { __fp16 __attribute__((ext_vector_type(2))) h; uint32_t u; } v;
  v.h = __builtin_amdgcn_cvt_pkrtz(a, b);
  return v.u;
}
__device__ __forceinline__ uint32_t packf16(float a, float b){
  union { _Float16 h[2]; uint32_t u; } v;
  v.h[0] = (_Float16)a; v.h[1] = (_Float16)b; return v.u;
}
__device__ __forceinline__ float sigmoidf_(float x){ return __fdividef(1.f, 1.f + __expf(-x)); }
__device__ __forceinline__ float siluf_(float x){ return x * __fdividef(1.f, 1.f + __expf(-x)); }
__device__ __forceinline__ float tanhf_(float x){
  float e = __expf(2.f*x);
  return 1.f - __fdividef(2.f, e + 1.f);
}

// ---- whh f32 -> thread-major packed f16 (R13 layout: 96 words x 256 thr) ----
__global__ __launch_bounds__(256) void cvtwt_kernel(const float* __restrict__ whh,
                                                    uint32_t* __restrict__ wT){
  const int n = NL*64*96*256;
  for (int idx = blockIdx.x*256 + threadIdx.x; idx < n; idx += gridDim.x*256){
    int tid = idx & 255;
    int rest = idx >> 8;
    int j = rest % 96;
    int rest2 = rest / 96;
    int g = rest2 & 63;
    int l = rest2 >> 6;
    int il = tid >> 4, ks = tid & 15;
    int i = g*16 + il;
    int G = j >> 5, jj = j & 31;
    int k = ks*64 + 2*jj;
    const float* src = whh + ((size_t)l*3072 + G*1024 + i)*1024 + k;
    wT[idx] = packf16(src[0], src[1]);
  }
}

// ---- per-slot fused residual+LN ----
__global__ __launch_bounds__(256) void lnres_slot(
    int slot, const float* __restrict__ x,
    const float* __restrict__ norm_w, const float* __restrict__ norm_b,
    float* __restrict__ hidden_ring,   // [NL][2][256][512]
    float* __restrict__ resid_ring,    // [NL][2][256][512]
    float* __restrict__ resid5,        // [4096][512]
    unsigned short* __restrict__ lnbf) // [NL][256][512]
{
  const int l = blockIdx.z, c = slot - l;
  if (c < 0 || c >= NCH) return;
  const int wave = threadIdx.x >> 6;
  const int lane = threadIdx.x & 63;
  const int r = blockIdx.x*4 + wave;
  const int b = r >> 6, dt = r & 63;
  const int tg = c*CHUNK + dt;
  const int p = c & 1;

  const float* hid = (l == 0) ? x + ((size_t)b*SEQ + tg)*DM + lane*8
                              : hidden_ring + (((size_t)(l-1)*2 + p)*256 + r)*DM + lane*8;
  float4 a0 = *(const float4*)hid;
  float4 a1 = *(const float4*)(hid + 4);
  if (l > 0){
    const float* rin = resid_ring + (((size_t)(l-1)*2 + p)*256 + r)*DM + lane*8;
    float4 b0 = *(const float4*)rin;
    float4 b1 = *(const float4*)(rin + 4);
    a0.x+=b0.x; a0.y+=b0.y; a0.z+=b0.z; a0.w+=b0.w;
    a1.x+=b1.x; a1.y+=b1.y; a1.z+=b1.z; a1.w+=b1.w;
  }
  float* rout = (l == 5) ? resid5 + ((size_t)b*SEQ + tg)*DM + lane*8
                         : resid_ring + (((size_t)l*2 + p)*256 + r)*DM + lane*8;
  *(float4*)rout = a0;
  *(float4*)(rout + 4) = a1;

  float xv[8] = {a0.x,a0.y,a0.z,a0.w,a1.x,a1.y,a1.z,a1.w};
  float s = 0.f, sq = 0.f;
  #pragma unroll
  for (int q=0;q<8;q++){ s += xv[q]; sq += xv[q]*xv[q]; }
  #pragma unroll
  for (int off=32; off; off>>=1){ s += __shfl_xor(s, off); sq += __shfl_xor(sq, off); }
  float mean = s * (1.f/DM);
  float var  = sq * (1.f/DM) - mean*mean;
  float rstd = rsqrtf(var + 1e-5f);
  const float* gamma = norm_w + l*DM;
  const float* beta  = norm_b + l*DM;
  float4 g0 = *(const float4*)(gamma + lane*8);
  float4 g1 = *(const float4*)(gamma + lane*8 + 4);
  float4 e0 = *(const float4*)(beta  + lane*8);
  float4 e1 = *(const float4*)(beta  + lane*8 + 4);
  float gv[8] = {g0.x,g0.y,g0.z,g0.w,g1.x,g1.y,g1.z,g1.w};
  float ev[8] = {e0.x,e0.y,e0.z,e0.w,e1.x,e1.y,e1.z,e1.w};
  uint4 pk;
  float y0 = (xv[0]-mean)*rstd*gv[0]+ev[0], y1 = (xv[1]-mean)*rstd*gv[1]+ev[1];
  float y2 = (xv[2]-mean)*rstd*gv[2]+ev[2], y3 = (xv[3]-mean)*rstd*gv[3]+ev[3];
  float y4 = (xv[4]-mean)*rstd*gv[4]+ev[4], y5 = (xv[5]-mean)*rstd*gv[5]+ev[5];
  float y6 = (xv[6]-mean)*rstd*gv[6]+ev[6], y7 = (xv[7]-mean)*rstd*gv[7]+ev[7];
  pk.x = (unsigned)f2bf(y0) | ((unsigned)f2bf(y1)<<16);
  pk.y = (unsigned)f2bf(y2) | ((unsigned)f2bf(y3)<<16);
  pk.z = (unsigned)f2bf(y4) | ((unsigned)f2bf(y5)<<16);
  pk.w = (unsigned)f2bf(y6) | ((unsigned)f2bf(y7)<<16);
  *(uint4*)(lnbf + ((size_t)l*256 + r)*DM + lane*8) = pk;
}

// ---- final layernorm (full 4096 rows) ----
__global__ __launch_bounds__(256) void ln_final(
    const float* __restrict__ hidden, const float* __restrict__ resid_in,
    const float* __restrict__ gamma,  const float* __restrict__ beta,
    float* __restrict__ out_f32)
{
  int wave = threadIdx.x >> 6;
  int lane = threadIdx.x & 63;
  int row  = blockIdx.x*4 + wave;
  size_t base = (size_t)row * DM + lane*8;
  float4 a0 = *(const float4*)(hidden + base);
  float4 a1 = *(const float4*)(hidden + base + 4);
  float4 b0 = *(const float4*)(resid_in + base);
  float4 b1 = *(const float4*)(resid_in + base + 4);
  a0.x+=b0.x; a0.y+=b0.y; a0.z+=b0.z; a0.w+=b0.w;
  a1.x+=b1.x; a1.y+=b1.y; a1.z+=b1.z; a1.w+=b1.w;
  float xv[8] = {a0.x,a0.y,a0.z,a0.w,a1.x,a1.y,a1.z,a1.w};
  float s = 0.f, sq = 0.f;
  #pragma unroll
  for (int q=0;q<8;q++){ s += xv[q]; sq += xv[q]*xv[q]; }
  #pragma unroll
  for (int off=32; off; off>>=1){ s += __shfl_xor(s, off); sq += __shfl_xor(sq, off); }
  float mean = s * (1.f/DM);
  float var  = sq * (1.f/DM) - mean*mean;
  float rstd = rsqrtf(var + 1e-5f);
  float4 g0 = *(const float4*)(gamma + lane*8);
  float4 g1 = *(const float4*)(gamma + lane*8 + 4);
  float4 e0 = *(const float4*)(beta  + lane*8);
  float4 e1 = *(const float4*)(beta  + lane*8 + 4);
  float gv[8] = {g0.x,g0.y,g0.z,g0.w,g1.x,g1.y,g1.z,g1.w};
  float ev[8] = {e0.x,e0.y,e0.z,e0.w,e1.x,e1.y,e1.z,e1.w};
  float4 o0, o1;
  o0.x=(xv[0]-mean)*rstd*gv[0]+ev[0]; o0.y=(xv[1]-mean)*rstd*gv[1]+ev[1];
  o0.z=(xv[2]-mean)*rstd*gv[2]+ev[2]; o0.w=(xv[3]-mean)*rstd*gv[3]+ev[3];
  o1.x=(xv[4]-mean)*rstd*gv[4]+ev[4]; o1.y=(xv[5]-mean)*rstd*gv[5]+ev[5];
  o1.z=(xv[6]-mean)*rstd*gv[6]+ev[6]; o1.w=(xv[7]-mean)*rstd*gv[7]+ev[7];
  *(float4*)(out_f32 + base)     = o0;
  *(float4*)(out_f32 + base + 4) = o1;
}

// ---- per-slot GEMM, A bf16 x B f32(on-the-fly->bf16)^T, M=256 ----
__device__ __forceinline__ bf16x8 ldcvt8(const float* p){
  float4 u = *(const float4*)p;
  float4 v = *(const float4*)(p + 4);
  bf16x8 r;
  r[0]=(short)f2bf(u.x); r[1]=(short)f2bf(u.y); r[2]=(short)f2bf(u.z); r[3]=(short)f2bf(u.w);
  r[4]=(short)f2bf(v.x); r[5]=(short)f2bf(v.y); r[6]=(short)f2bf(v.z); r[7]=(short)f2bf(v.w);
  return r;
}
__global__ __launch_bounds__(256) void gemm_slot(
    int op, int slot,
    const unsigned short* __restrict__ lnbf, const float* __restrict__ inw,
    const float* __restrict__ inb, float* __restrict__ xz_ring,
    const unsigned short* __restrict__ xconvb, const float* __restrict__ wih,
    const float* __restrict__ bih, unsigned short* __restrict__ xihb,
    const unsigned short* __restrict__ xoutb, const float* __restrict__ outw,
    const float* __restrict__ outb, float* __restrict__ hidden_ring,
    float* __restrict__ hidden5)
{
  const int l = blockIdx.z, c = slot - l;
  if (c < 0 || c >= NCH) return;

  const unsigned short* A; const float* Bf; const float* bias;
  int N, K;
  if (op == 0){ A = lnbf   + (size_t)l*256*DM;  Bf = inw  + (size_t)l*2048*512;  bias = inb  + l*2048; N = 2048; K = 512; }
  else if (op == 1){ A = xconvb + (size_t)l*256*DI; Bf = wih  + (size_t)l*3072*1024; bias = bih  + l*3072; N = 3072; K = 1024; }
  else { A = xoutb  + (size_t)l*256*DI; Bf = outw + (size_t)l*512*1024;  bias = outb + l*512;  N = 512;  K = 1024; }

  const int tid  = threadIdx.x;
  const int wid  = tid >> 6, lane = tid & 63;
  const int wm   = wid >> 1, wn = wid & 1;
  const int tm   = blockIdx.y*128 + wm*64;
  const int tn   = blockIdx.x*128 + wn*64;
  const int l15  = lane & 15;
  const int lk   = (lane >> 4) * 8;

  f32x4 acc[4][4] = {};
  for (int kk = 0; kk < K; kk += 32){
    bf16x8 a[4], b[4];
    #pragma unroll
    for (int f=0; f<4; ++f)
      a[f] = *(const bf16x8*)(A + (size_t)(tm + f*16 + l15)*K + kk + lk);
    #pragma unroll
    for (int f=0; f<4; ++f)
      b[f] = ldcvt8(Bf + (size_t)(tn + f*16 + l15)*K + kk + lk);
    #pragma unroll
    for (int i=0;i<4;i++)
      #pragma unroll
      for (int j=0;j<4;j++)
        acc[i][j] = __builtin_amdgcn_mfma_f32_16x16x32_bf16(a[i], b[j], acc[i][j], 0,0,0);
  }
  const int crow0 = (lane>>4)*4;
  const int p = c & 1;
  #pragma unroll
  for (int i=0;i<4;i++){
    #pragma unroll
    for (int j=0;j<4;j++){
      int col = tn + j*16 + l15;
      float bv = bias[col];
      #pragma unroll
      for (int r=0;r<4;r++){
        int row = tm + i*16 + crow0 + r;
        float val = acc[i][j][r] + bv;
        if (op == 0){
          xz_ring[(((size_t)l*2 + p)*256 + row)*2048 + col] = val;
        } else if (op == 1){
          xihb[((size_t)l*256 + row)*3072 + col] = f2bf(val);
        } else {
          if (l == 5){
            int b_ = row >> 6, dt = row & 63;
            hidden5[((size_t)b_*SEQ + c*CHUNK + dt)*DM + col] = val;
          } else {
            hidden_ring[(((size_t)l*2 + p)*256 + row)*DM + col] = val;
          }
        }
      }
    }
  }
}

// ---- per-slot causal conv(4)+SiLU, 8-wide vectorized ----
__global__ __launch_bounds__(256) void conv_slot(
    int slot, const float* __restrict__ xz_ring,
    const float* __restrict__ cw, const float* __restrict__ cb,
    unsigned short* __restrict__ xconvb)
{
  const int l = blockIdx.z, c = slot - l;
  if (c < 0 || c >= NCH) return;
  const int idx = blockIdx.x*256 + threadIdx.x;   // 0..32767
  const int ch0 = (idx & 127) * 8;
  const int r   = idx >> 7;                       // 0..255
  const int b   = r >> 6, dt = r & 63;
  const int tg  = c*CHUNK + dt;
  const int p   = c & 1;

  const float* base = xz_ring + ((size_t)l*2)*256*2048;
  float xt[4][8];
  { const float* pr = base + ((size_t)p*256 + r)*2048 + ch0;
    *(float4*)&xt[0][0] = *(const float4*)pr;
    *(float4*)&xt[0][4] = *(const float4*)(pr + 4); }
  #pragma unroll
  for (int k=1;k<=3;k++){
    if (tg >= k){
      int dtk = dt - k;
      int pp = (dtk >= 0) ? p : (p^1);
      int rr = b*64 + ((dtk + 64) & 63);
      const float* pr = base + ((size_t)pp*256 + rr)*2048 + ch0;
      *(float4*)&xt[k][0] = *(const float4*)pr;
      *(float4*)&xt[k][4] = *(const float4*)(pr + 4);
    } else {
      #pragma unroll
      for (int j=0;j<8;j++) xt[k][j] = 0.f;
    }
  }
  const float* cbp = cb + l*DI + ch0;
  float cbv[8];
  *(float4*)&cbv[0] = *(const float4*)cbp;
  *(float4*)&cbv[4] = *(const float4*)(cbp + 4);

  unsigned short ov[8];
  #pragma unroll
  for (int j=0;j<8;j++){
    float4 wv = *(const float4*)(cw + ((size_t)(l*DI + ch0 + j))*4);
    float acc = cbv[j] + xt[0][j]*wv.w + xt[1][j]*wv.z + xt[2][j]*wv.y + xt[3][j]*wv.x;
    ov[j] = f2bf(siluf_(acc));
  }
  uint4 pk;
  pk.x = (unsigned)ov[0] | ((unsigned)ov[1]<<16);
  pk.y = (unsigned)ov[2] | ((unsigned)ov[3]<<16);
  pk.z = (unsigned)ov[4] | ((unsigned)ov[5]<<16);
  pk.w = (unsigned)ov[6] | ((unsigned)ov[7]<<16);
  *(uint4*)(xconvb + ((size_t)l*256 + r)*DI + ch0) = pk;
}

// ---- wavefront scan slot: 6 layers x 64 wgs x 256 thr; 4 batches/wg ----
// R17 structure (proven 340us) + s_sleep(2) fine-grain poll retry +
// s_setprio(1) around the dot/reduce (spin waves yield to compute waves).
__global__ __launch_bounds__(256, 2) void scan_slot(
    int slot,
    const unsigned short* __restrict__ xihb,   // [NL][256][3072]
    const float* __restrict__ xz_ring,         // [NL][2][256][2048]
    const uint32_t* __restrict__ wT,           // thread-major packed f16
    const float* __restrict__ bhh,             // [NL][3072]
    uint32_t* __restrict__ hbufs,              // [NL][2][1024][4] {f16|tag}
    unsigned short* __restrict__ xoutb)        // [NL][256][1024]
{
  const int w = blockIdx.x;
  const int l = w >> 6;
  const int g = w & 63;
  const int c = slot - l;
  if (c < 0 || c >= NCH) return;

  const int tid = threadIdx.x;
  const int il  = tid >> 4;          // 0..15
  const int ks  = tid & 15;          // 0..15 (64-wide h slice)
  const int i   = g*16 + il;

  const uint32_t* pw = wT + ((size_t)(l*64 + g)*96)*256 + tid;
  uint32_t wrp[32], wzp[32], wnp[32];
  #pragma unroll
  for (int j=0;j<32;j++) wrp[j] = pw[(size_t)j*256];
  #pragma unroll
  for (int j=0;j<32;j++) wzp[j] = pw[(size_t)(32+j)*256];
  #pragma unroll
  for (int j=0;j<32;j++) wnp[j] = pw[(size_t)(64+j)*256];

  const float* bh = bhh + l*3072;
  const float bhr = bh[i], bhz = bh[DI+i], bhn = bh[2*DI+i];

  __shared__ uint32_t hshw[2][NB][16*36];   // parity, batch plane, 16 rows x 36 u32

  const uint32_t lbase = (uint32_t)l << 10;
  uint32_t* hb = hbufs + (size_t)l*2*4096;
  const unsigned short* xih = xihb + (size_t)l*256*3072;
  const float* xzp = xz_ring + ((size_t)(l*2 + (c&1))*256)*2048;
  unsigned short* xo = xoutb + (size_t)l*256*DI;

  // lane ks<4 owns batch ks: scalar x regs + scalar hprev
  float xr_c=0.f, xzg_c=0.f, xn_c=0.f, zg_c=0.f;
  float xr_n=0.f, xzg_n=0.f, xn_n=0.f, zg_n=0.f;
  float hprev = 0.f;
  if (ks < 4){
    int r = ks*64;
    xr_c  = bf2f(xih[(size_t)r*3072 + i]);
    xzg_c = bf2f(xih[(size_t)r*3072 + DI + i]);
    xn_c  = bf2f(xih[(size_t)r*3072 + 2*DI + i]);
    zg_c  = xzp[(size_t)r*2048 + DI + i];
  }

  const int r0 = tid >> 6;         // base LDS row of this thread's polled i's
  const int c0 = tid & 63;         // u16 column

  for (int dt=0; dt<CHUNK; ++dt){
    const int t   = c*CHUNK + dt;
    const int par = t & 1;
    if (t == 0){
      uint32_t* hz = &hshw[0][0][0];
      for (int j=tid; j<NB*16*36; j+=256) hz[j] = 0u;
    } else {
      const uint32_t want = lbase + (uint32_t)t;
      const uintptr_t p = (uintptr_t)(hb + (size_t)par*4096 + 4*tid);
      u32x4 A0, A1, A2, A3;
      asm volatile("global_load_dwordx4 %0, %4, off sc1\n\t"
                   "global_load_dwordx4 %1, %5, off sc1\n\t"
                   "global_load_dwordx4 %2, %6, off sc1\n\t"
                   "global_load_dwordx4 %3, %7, off sc1\n\t"
                   "s_waitcnt vmcnt(0)"
                   : "=&v"(A0), "=&v"(A1), "=&v"(A2), "=&v"(A3)
                   : "v"(p), "v"(p+4096), "v"(p+8192), "v"(p+12288));
      while (((A0[0]>>16)<want)|((A0[1]>>16)<want)|((A0[2]>>16)<want)|((A0[3]>>16)<want)|
             ((A1[0]>>16)<want)|((A1[1]>>16)<want)|((A1[2]>>16)<want)|((A1[3]>>16)<want)|
             ((A2[0]>>16)<want)|((A2[1]>>16)<want)|((A2[2]>>16)<want)|((A2[3]>>16)<want)|
             ((A3[0]>>16)<want)|((A3[1]>>16)<want)|((A3[2]>>16)<want)|((A3[3]>>16)<want)){
        __builtin_amdgcn_s_sleep(2);
        asm volatile("global_load_dwordx4 %0, %4, off sc1\n\t"
                     "global_load_dwordx4 %1, %5, off sc1\n\t"
                     "global_load_dwordx4 %2, %6, off sc1\n\t"
                     "global_load_dwordx4 %3, %7, off sc1\n\t"
                     "s_waitcnt vmcnt(0)"
                     : "=&v"(A0), "=&v"(A1), "=&v"(A2), "=&v"(A3)
                     : "v"(p), "v"(p+4096), "v"(p+8192), "v"(p+12288));
      }
      uint16_t* hp16 = (uint16_t*)&hshw[par][0][0];   // plane stride 1152 u16
      #pragma unroll
      for (int b4=0;b4<NB;b4++){
        hp16[b4*1152 + (r0+ 0)*72 + c0] = (uint16_t)A0[b4];
        hp16[b4*1152 + (r0+ 4)*72 + c0] = (uint16_t)A1[b4];
        hp16[b4*1152 + (r0+ 8)*72 + c0] = (uint16_t)A2[b4];
        hp16[b4*1152 + (r0+12)*72 + c0] = (uint16_t)A3[b4];
      }
    }
    __syncthreads();     // hshw[par] ready

    if (ks < 4 && dt == 0 && c > 0){
      const uint16_t* hp16 = (const uint16_t*)&hshw[par][0][0];
      union { uint16_t u; _Float16 h; } hv;
      hv.u = hp16[ks*1152 + (i>>6)*72 + (i&63)];
      hprev = (float)hv.h;
    }
    if (ks < 4 && dt+1 < CHUNK){
      int r = ks*64 + dt + 1;
      xr_n  = bf2f(xih[(size_t)r*3072 + i]);
      xzg_n = bf2f(xih[(size_t)r*3072 + DI + i]);
      xn_n  = bf2f(xih[(size_t)r*3072 + 2*DI + i]);
      zg_n  = xzp[(size_t)r*2048 + DI + i];
    }

    __builtin_amdgcn_s_setprio(1);
    float ar[NB] = {0,0,0,0}, az[NB] = {0,0,0,0}, an[NB] = {0,0,0,0};
    #pragma unroll
    for (int q=0;q<8;q++){
      #pragma unroll
      for (int b4=0;b4<NB;b4++){
        u32x4 hv = *(const u32x4*)&hshw[par][b4][ks*36 + 4*q];
        ar[b4] = __builtin_amdgcn_fdot2(u2h(wrp[4*q+0]), u2h(hv[0]), ar[b4], false);
        az[b4] = __builtin_amdgcn_fdot2(u2h(wzp[4*q+0]), u2h(hv[0]), az[b4], false);
        an[b4] = __builtin_amdgcn_fdot2(u2h(wnp[4*q+0]), u2h(hv[0]), an[b4], false);
        ar[b4] = __builtin_amdgcn_fdot2(u2h(wrp[4*q+1]), u2h(hv[1]), ar[b4], false);
        az[b4] = __builtin_amdgcn_fdot2(u2h(wzp[4*q+1]), u2h(hv[1]), az[b4], false);
        an[b4] = __builtin_amdgcn_fdot2(u2h(wnp[4*q+1]), u2h(hv[1]), an[b4], false);
        ar[b4] = __builtin_amdgcn_fdot2(u2h(wrp[4*q+2]), u2h(hv[2]), ar[b4], false);
        az[b4] = __builtin_amdgcn_fdot2(u2h(wzp[4*q+2]), u2h(hv[2]), az[b4], false);
        an[b4] = __builtin_amdgcn_fdot2(u2h(wnp[4*q+2]), u2h(hv[2]), an[b4], false);
        ar[b4] = __builtin_amdgcn_fdot2(u2h(wrp[4*q+3]), u2h(hv[3]), ar[b4], false);
        az[b4] = __builtin_amdgcn_fdot2(u2h(wzp[4*q+3]), u2h(hv[3]), az[b4], false);
        an[b4] = __builtin_amdgcn_fdot2(u2h(wnp[4*q+3]), u2h(hv[3]), an[b4], false);
      }
    }
    #pragma unroll
    for (int off=1; off<16; off<<=1){
      #pragma unroll
      for (int b4=0;b4<NB;b4++){
        ar[b4] += __shfl_xor(ar[b4], off);
        az[b4] += __shfl_xor(az[b4], off);
        an[b4] += __shfl_xor(an[b4], off);
      }
    }
    __builtin_amdgcn_s_setprio(0);

    if (ks < 4){
      const int b4 = ks;
      float r_ = sigmoidf_(xr_c + ar[b4] + bhr);
      float z_ = sigmoidf_(xzg_c + az[b4] + bhz);
      float n_ = tanhf_(xn_c + r_*(an[b4] + bhn));
      float hnew = (1.f - z_)*n_ + z_*hprev;
      hprev = hnew;
      uint32_t hw = (pkrtz2u(hnew, 0.f) & 0xffffu)
                  | ((lbase + (uint32_t)t + 1u) << 16);
      const uintptr_t hdst = (uintptr_t)(hb + (size_t)((t+1)&1)*4096 + 4*i + b4);
      asm volatile("global_store_dword %0, %1, off sc1"
                   :: "v"(hdst), "v"(hw));
      int r = b4*64 + dt;
      xo[(size_t)r*DI + i] = f2bf(hnew * siluf_(zg_c));
      xr_c = xr_n; xzg_c = xzg_n; xn_c = xn_n; zg_c = zg_n;
    }
  }
}

// ---------------- host ----------------
extern "C" void kernel_launch(void* const* d_in, const int* in_sizes, int n_in,
                              void* d_out, int out_size, void* d_ws, size_t ws_size,
                              hipStream_t stream)
{
  (void)in_sizes; (void)n_in; (void)out_size; (void)ws_size;
  const float* x      = (const float*)d_in[0];
  const float* norm_w = (const float*)d_in[1];
  const float* norm_b = (const float*)d_in[2];
  const float* inw    = (const float*)d_in[3];
  const float* inb    = (const float*)d_in[4];
  const float* convw  = (const float*)d_in[5];
  const float* convb  = (const float*)d_in[6];
  const float* wih    = (const float*)d_in[7];
  const float* whh    = (const float*)d_in[8];
  const float* bih    = (const float*)d_in[9];
  const float* bhh    = (const float*)d_in[10];
  const float* outw   = (const float*)d_in[11];
  const float* outb   = (const float*)d_in[12];
  const float* normfw = (const float*)d_in[13];
  const float* normfb = (const float*)d_in[14];
  float* out = (float*)d_out;

  char* ws = (char*)d_ws;
  size_t off = 0;
  auto alloc = [&](size_t bytes)->void*{ void* p = ws + off; off = (off + bytes + 255) & ~(size_t)255; return p; };
  uint32_t*       wT      = (uint32_t*)      alloc((size_t)NL*64*96*256*4);
  unsigned short* lnbf    = (unsigned short*)alloc((size_t)NL*256*DM*2);
  float*          xz_ring = (float*)         alloc((size_t)NL*2*256*2048*4);
  unsigned short* xconvb  = (unsigned short*)alloc((size_t)NL*256*DI*2);
  unsigned short* xihb    = (unsigned short*)alloc((size_t)NL*256*3072*2);
  unsigned short* xoutb   = (unsigned short*)alloc((size_t)NL*256*DI*2);
  float*          resid_ring  = (float*)     alloc((size_t)NL*2*256*DM*4);
  float*          hidden_ring = (float*)     alloc((size_t)NL*2*256*DM*4);
  float*          resid5  = (float*)         alloc((size_t)BT*DM*4);
  float*          hidden5 = (float*)         alloc((size_t)BT*DM*4);
  uint32_t*       hbufs   = (uint32_t*)      alloc((size_t)NL*2*4096*4);

  hipMemsetAsync(hbufs, 0, (size_t)NL*2*4096*4, stream);
  cvtwt_kernel<<<2048, 256, 0, stream>>>(whh, wT);

  for (int slot = 0; slot < NSLOT; ++slot){
    lnres_slot<<<dim3(64,1,NL), 256, 0, stream>>>(slot, x, norm_w, norm_b,
                                                  hidden_ring, resid_ring, resid5, lnbf);
    gemm_slot<<<dim3(16,2,NL), 256, 0, stream>>>(0, slot, lnbf, inw, inb, xz_ring,
                                                 xconvb, wih, bih, xihb,
                                                 xoutb, outw, outb, hidden_ring, hidden5);
    conv_slot<<<dim3(128,1,NL), 256, 0, stream>>>(slot, xz_ring, convw, convb, xconvb);
    gemm_slot<<<dim3(24,2,NL), 256, 0, stream>>>(1, slot, lnbf, inw, inb, xz_ring,
                                                 xconvb, wih, bih, xihb,
                                                 xoutb, outw, outb, hidden_ring, hidden5);
    scan_slot<<<dim3(NL*64), 256, 0, stream>>>(slot, xihb, xz_ring, wT, bhh, hbufs, xoutb);
    gemm_slot<<<dim3(4,2,NL), 256, 0, stream>>>(2, slot, lnbf, inw, inb, xz_ring,
                                                xconvb, wih, bih, xihb,
                                                xoutb, outw, outb, hidden_ring, hidden5);
  }
  ln_final<<<1024, 256, 0, stream>>>(hidden5, resid5, normfw, normfb, out);
}

// Round 19
// 9902.872 us; speedup vs baseline: 1.3336x; 1.0067x over previous
//
#include <hip/hip_runtime.h>
#include <hip/hip_bf16.h>
#include <stdint.h>

#define SEQ   1024
#define NB    4
#define BT    4096
#define DM    512
#define DI    1024
#define NL    6
#define CHUNK 64
#define NCH   16          // SEQ/CHUNK
#define NSLOT (NL + NCH - 1)

typedef float  f32x4  __attribute__((ext_vector_type(4)));
typedef short  bf16x8 __attribute__((ext_vector_type(8)));
typedef _Float16 f16x2 __attribute__((ext_vector_type(2)));
typedef uint32_t u32x4 __attribute__((ext_vector_type(4)));

__device__ __forceinline__ float bf2f(unsigned short u){
  union { unsigned int i; float f; } v; v.i = ((unsigned int)u) << 16; return v.f;
}
__device__ __forceinline__ unsigned short f2bf(float f){
  union { float f; unsigned int i; } v; v.f = f;
  unsigned int x = v.i;
  return (unsigned short)((x + 0x7fffu + ((x >> 16) & 1u)) >> 16);
}
__device__ __forceinline__ float bits2f(uint32_t u){
  union { uint32_t i; float f; } v; v.i = u; return v.f;
}
__device__ __forceinline__ f16x2 u2h(uint32_t u){
  union { uint32_t u; f16x2 h; } v; v.u = u; return v.h;
}
__device__ __forceinline__ uint32_t pkrtz2u(float a, float b){
  union { __fp16 __attribute__((ext_vector_type(2))) h; uint32_t u; } v;
  v.h = __builtin_amdgcn_cvt_pkrtz(a, b);
  return v.u;
}
__device__ __forceinline__ uint32_t packf16(float a, float b){
  union { _Float16 h[2]; uint32_t u; } v;
  v.h[0] = (_Float16)a; v.h[1] = (_Float16)b; return v.u;
}
__device__ __forceinline__ float sigmoidf_(float x){ return __fdividef(1.f, 1.f + __expf(-x)); }
__device__ __forceinline__ float siluf_(float x){ return x * __fdividef(1.f, 1.f + __expf(-x)); }
__device__ __forceinline__ float tanhf_(float x){
  float e = __expf(2.f*x);
  return 1.f - __fdividef(2.f, e + 1.f);
}

// ---- whh f32 -> thread-major packed f16 (R13 layout: 96 words x 256 thr) ----
__global__ __launch_bounds__(256) void cvtwt_kernel(const float* __restrict__ whh,
                                                    uint32_t* __restrict__ wT){
  const int n = NL*64*96*256;
  for (int idx = blockIdx.x*256 + threadIdx.x; idx < n; idx += gridDim.x*256){
    int tid = idx & 255;
    int rest = idx >> 8;
    int j = rest % 96;
    int rest2 = rest / 96;
    int g = rest2 & 63;
    int l = rest2 >> 6;
    int il = tid >> 4, ks = tid & 15;
    int i = g*16 + il;
    int G = j >> 5, jj = j & 31;
    int k = ks*64 + 2*jj;
    const float* src = whh + ((size_t)l*3072 + G*1024 + i)*1024 + k;
    wT[idx] = packf16(src[0], src[1]);
  }
}

// ---- f32 -> bf16 bulk weight conversion ----
__global__ __launch_bounds__(256) void cvtbf_kernel(const float* __restrict__ in,
                                                    unsigned short* __restrict__ out, int n){
  int i = blockIdx.x*256 + threadIdx.x;
  int stride = gridDim.x*256;
  for (; i < n; i += stride) out[i] = f2bf(in[i]);
}

// ---- per-slot fused residual+LN ----
__global__ __launch_bounds__(256) void lnres_slot(
    int slot, const float* __restrict__ x,
    const float* __restrict__ norm_w, const float* __restrict__ norm_b,
    float* __restrict__ hidden_ring,   // [NL][2][256][512]
    float* __restrict__ resid_ring,    // [NL][2][256][512]
    float* __restrict__ resid5,        // [4096][512]
    unsigned short* __restrict__ lnbf) // [NL][256][512]
{
  const int l = blockIdx.z, c = slot - l;
  if (c < 0 || c >= NCH) return;
  const int wave = threadIdx.x >> 6;
  const int lane = threadIdx.x & 63;
  const int r = blockIdx.x*4 + wave;
  const int b = r >> 6, dt = r & 63;
  const int tg = c*CHUNK + dt;
  const int p = c & 1;

  const float* hid = (l == 0) ? x + ((size_t)b*SEQ + tg)*DM + lane*8
                              : hidden_ring + (((size_t)(l-1)*2 + p)*256 + r)*DM + lane*8;
  float4 a0 = *(const float4*)hid;
  float4 a1 = *(const float4*)(hid + 4);
  if (l > 0){
    const float* rin = resid_ring + (((size_t)(l-1)*2 + p)*256 + r)*DM + lane*8;
    float4 b0 = *(const float4*)rin;
    float4 b1 = *(const float4*)(rin + 4);
    a0.x+=b0.x; a0.y+=b0.y; a0.z+=b0.z; a0.w+=b0.w;
    a1.x+=b1.x; a1.y+=b1.y; a1.z+=b1.z; a1.w+=b1.w;
  }
  float* rout = (l == 5) ? resid5 + ((size_t)b*SEQ + tg)*DM + lane*8
                         : resid_ring + (((size_t)l*2 + p)*256 + r)*DM + lane*8;
  *(float4*)rout = a0;
  *(float4*)(rout + 4) = a1;

  float xv[8] = {a0.x,a0.y,a0.z,a0.w,a1.x,a1.y,a1.z,a1.w};
  float s = 0.f, sq = 0.f;
  #pragma unroll
  for (int q=0;q<8;q++){ s += xv[q]; sq += xv[q]*xv[q]; }
  #pragma unroll
  for (int off=32; off; off>>=1){ s += __shfl_xor(s, off); sq += __shfl_xor(sq, off); }
  float mean = s * (1.f/DM);
  float var  = sq * (1.f/DM) - mean*mean;
  float rstd = rsqrtf(var + 1e-5f);
  const float* gamma = norm_w + l*DM;
  const float* beta  = norm_b + l*DM;
  float4 g0 = *(const float4*)(gamma + lane*8);
  float4 g1 = *(const float4*)(gamma + lane*8 + 4);
  float4 e0 = *(const float4*)(beta  + lane*8);
  float4 e1 = *(const float4*)(beta  + lane*8 + 4);
  float gv[8] = {g0.x,g0.y,g0.z,g0.w,g1.x,g1.y,g1.z,g1.w};
  float ev[8] = {e0.x,e0.y,e0.z,e0.w,e1.x,e1.y,e1.z,e1.w};
  uint4 pk;
  float y0 = (xv[0]-mean)*rstd*gv[0]+ev[0], y1 = (xv[1]-mean)*rstd*gv[1]+ev[1];
  float y2 = (xv[2]-mean)*rstd*gv[2]+ev[2], y3 = (xv[3]-mean)*rstd*gv[3]+ev[3];
  float y4 = (xv[4]-mean)*rstd*gv[4]+ev[4], y5 = (xv[5]-mean)*rstd*gv[5]+ev[5];
  float y6 = (xv[6]-mean)*rstd*gv[6]+ev[6], y7 = (xv[7]-mean)*rstd*gv[7]+ev[7];
  pk.x = (unsigned)f2bf(y0) | ((unsigned)f2bf(y1)<<16);
  pk.y = (unsigned)f2bf(y2) | ((unsigned)f2bf(y3)<<16);
  pk.z = (unsigned)f2bf(y4) | ((unsigned)f2bf(y5)<<16);
  pk.w = (unsigned)f2bf(y6) | ((unsigned)f2bf(y7)<<16);
  *(uint4*)(lnbf + ((size_t)l*256 + r)*DM + lane*8) = pk;
}

// ---- final layernorm (full 4096 rows) ----
__global__ __launch_bounds__(256) void ln_final(
    const float* __restrict__ hidden, const float* __restrict__ resid_in,
    const float* __restrict__ gamma,  const float* __restrict__ beta,
    float* __restrict__ out_f32)
{
  int wave = threadIdx.x >> 6;
  int lane = threadIdx.x & 63;
  int row  = blockIdx.x*4 + wave;
  size_t base = (size_t)row * DM + lane*8;
  float4 a0 = *(const float4*)(hidden + base);
  float4 a1 = *(const float4*)(hidden + base + 4);
  float4 b0 = *(const float4*)(resid_in + base);
  float4 b1 = *(const float4*)(resid_in + base + 4);
  a0.x+=b0.x; a0.y+=b0.y; a0.z+=b0.z; a0.w+=b0.w;
  a1.x+=b1.x; a1.y+=b1.y; a1.z+=b1.z; a1.w+=b1.w;
  float xv[8] = {a0.x,a0.y,a0.z,a0.w,a1.x,a1.y,a1.z,a1.w};
  float s = 0.f, sq = 0.f;
  #pragma unroll
  for (int q=0;q<8;q++){ s += xv[q]; sq += xv[q]*xv[q]; }
  #pragma unroll
  for (int off=32; off; off>>=1){ s += __shfl_xor(s, off); sq += __shfl_xor(sq, off); }
  float mean = s * (1.f/DM);
  float var  = sq * (1.f/DM) - mean*mean;
  float rstd = rsqrtf(var + 1e-5f);
  float4 g0 = *(const float4*)(gamma + lane*8);
  float4 g1 = *(const float4*)(gamma + lane*8 + 4);
  float4 e0 = *(const float4*)(beta  + lane*8);
  float4 e1 = *(const float4*)(beta  + lane*8 + 4);
  float gv[8] = {g0.x,g0.y,g0.z,g0.w,g1.x,g1.y,g1.z,g1.w};
  float ev[8] = {e0.x,e0.y,e0.z,e0.w,e1.x,e1.y,e1.z,e1.w};
  float4 o0, o1;
  o0.x=(xv[0]-mean)*rstd*gv[0]+ev[0]; o0.y=(xv[1]-mean)*rstd*gv[1]+ev[1];
  o0.z=(xv[2]-mean)*rstd*gv[2]+ev[2]; o0.w=(xv[3]-mean)*rstd*gv[3]+ev[3];
  o1.x=(xv[4]-mean)*rstd*gv[4]+ev[4]; o1.y=(xv[5]-mean)*rstd*gv[5]+ev[5];
  o1.z=(xv[6]-mean)*rstd*gv[6]+ev[6]; o1.w=(xv[7]-mean)*rstd*gv[7]+ev[7];
  *(float4*)(out_f32 + base)     = o0;
  *(float4*)(out_f32 + base + 4) = o1;
}

// ---- per-slot GEMM, A bf16; B: op1 = pre-converted bf16, op0/2 = f32 on-the-fly ----
__device__ __forceinline__ bf16x8 ldcvt8(const float* p){
  float4 u = *(const float4*)p;
  float4 v = *(const float4*)(p + 4);
  bf16x8 r;
  r[0]=(short)f2bf(u.x); r[1]=(short)f2bf(u.y); r[2]=(short)f2bf(u.z); r[3]=(short)f2bf(u.w);
  r[4]=(short)f2bf(v.x); r[5]=(short)f2bf(v.y); r[6]=(short)f2bf(v.z); r[7]=(short)f2bf(v.w);
  return r;
}
__global__ __launch_bounds__(256) void gemm_slot(
    int op, int slot,
    const unsigned short* __restrict__ lnbf, const float* __restrict__ inw,
    const float* __restrict__ inb, float* __restrict__ xz_ring,
    const unsigned short* __restrict__ xconvb, const unsigned short* __restrict__ wihbf,
    const float* __restrict__ bih, unsigned short* __restrict__ xihb,
    const unsigned short* __restrict__ xoutb, const float* __restrict__ outw,
    const float* __restrict__ outb, float* __restrict__ hidden_ring,
    float* __restrict__ hidden5)
{
  const int l = blockIdx.z, c = slot - l;
  if (c < 0 || c >= NCH) return;

  const unsigned short* A; const float* Bf = nullptr;
  const unsigned short* Bh = nullptr; const float* bias;
  int N, K;
  if (op == 0){ A = lnbf   + (size_t)l*256*DM;  Bf = inw   + (size_t)l*2048*512;  bias = inb  + l*2048; N = 2048; K = 512; }
  else if (op == 1){ A = xconvb + (size_t)l*256*DI; Bh = wihbf + (size_t)l*3072*1024; bias = bih  + l*3072; N = 3072; K = 1024; }
  else { A = xoutb  + (size_t)l*256*DI; Bf = outw  + (size_t)l*512*1024;  bias = outb + l*512;  N = 512;  K = 1024; }

  const int tid  = threadIdx.x;
  const int wid  = tid >> 6, lane = tid & 63;
  const int wm   = wid >> 1, wn = wid & 1;
  const int tm   = blockIdx.y*128 + wm*64;
  const int tn   = blockIdx.x*128 + wn*64;
  const int l15  = lane & 15;
  const int lk   = (lane >> 4) * 8;

  f32x4 acc[4][4] = {};
  for (int kk = 0; kk < K; kk += 32){
    bf16x8 a[4], b[4];
    #pragma unroll
    for (int f=0; f<4; ++f)
      a[f] = *(const bf16x8*)(A + (size_t)(tm + f*16 + l15)*K + kk + lk);
    if (op == 1){
      #pragma unroll
      for (int f=0; f<4; ++f)
        b[f] = *(const bf16x8*)(Bh + (size_t)(tn + f*16 + l15)*K + kk + lk);
    } else {
      #pragma unroll
      for (int f=0; f<4; ++f)
        b[f] = ldcvt8(Bf + (size_t)(tn + f*16 + l15)*K + kk + lk);
    }
    #pragma unroll
    for (int i=0;i<4;i++)
      #pragma unroll
      for (int j=0;j<4;j++)
        acc[i][j] = __builtin_amdgcn_mfma_f32_16x16x32_bf16(a[i], b[j], acc[i][j], 0,0,0);
  }
  const int crow0 = (lane>>4)*4;
  const int p = c & 1;
  #pragma unroll
  for (int i=0;i<4;i++){
    #pragma unroll
    for (int j=0;j<4;j++){
      int col = tn + j*16 + l15;
      float bv = bias[col];
      #pragma unroll
      for (int r=0;r<4;r++){
        int row = tm + i*16 + crow0 + r;
        float val = acc[i][j][r] + bv;
        if (op == 0){
          xz_ring[(((size_t)l*2 + p)*256 + row)*2048 + col] = val;
        } else if (op == 1){
          xihb[((size_t)l*256 + row)*3072 + col] = f2bf(val);
        } else {
          if (l == 5){
            int b_ = row >> 6, dt = row & 63;
            hidden5[((size_t)b_*SEQ + c*CHUNK + dt)*DM + col] = val;
          } else {
            hidden_ring[(((size_t)l*2 + p)*256 + row)*DM + col] = val;
          }
        }
      }
    }
  }
}

// ---- per-slot causal conv(4)+SiLU, 8-wide vectorized ----
__global__ __launch_bounds__(256) void conv_slot(
    int slot, const float* __restrict__ xz_ring,
    const float* __restrict__ cw, const float* __restrict__ cb,
    unsigned short* __restrict__ xconvb)
{
  const int l = blockIdx.z, c = slot - l;
  if (c < 0 || c >= NCH) return;
  const int idx = blockIdx.x*256 + threadIdx.x;   // 0..32767
  const int ch0 = (idx & 127) * 8;
  const int r   = idx >> 7;                       // 0..255
  const int b   = r >> 6, dt = r & 63;
  const int tg  = c*CHUNK + dt;
  const int p   = c & 1;

  const float* base = xz_ring + ((size_t)l*2)*256*2048;
  float xt[4][8];
  { const float* pr = base + ((size_t)p*256 + r)*2048 + ch0;
    *(float4*)&xt[0][0] = *(const float4*)pr;
    *(float4*)&xt[0][4] = *(const float4*)(pr + 4); }
  #pragma unroll
  for (int k=1;k<=3;k++){
    if (tg >= k){
      int dtk = dt - k;
      int pp = (dtk >= 0) ? p : (p^1);
      int rr = b*64 + ((dtk + 64) & 63);
      const float* pr = base + ((size_t)pp*256 + rr)*2048 + ch0;
      *(float4*)&xt[k][0] = *(const float4*)pr;
      *(float4*)&xt[k][4] = *(const float4*)(pr + 4);
    } else {
      #pragma unroll
      for (int j=0;j<8;j++) xt[k][j] = 0.f;
    }
  }
  const float* cbp = cb + l*DI + ch0;
  float cbv[8];
  *(float4*)&cbv[0] = *(const float4*)cbp;
  *(float4*)&cbv[4] = *(const float4*)(cbp + 4);

  unsigned short ov[8];
  #pragma unroll
  for (int j=0;j<8;j++){
    float4 wv = *(const float4*)(cw + ((size_t)(l*DI + ch0 + j))*4);
    float acc = cbv[j] + xt[0][j]*wv.w + xt[1][j]*wv.z + xt[2][j]*wv.y + xt[3][j]*wv.x;
    ov[j] = f2bf(siluf_(acc));
  }
  uint4 pk;
  pk.x = (unsigned)ov[0] | ((unsigned)ov[1]<<16);
  pk.y = (unsigned)ov[2] | ((unsigned)ov[3]<<16);
  pk.z = (unsigned)ov[4] | ((unsigned)ov[5]<<16);
  pk.w = (unsigned)ov[6] | ((unsigned)ov[7]<<16);
  *(uint4*)(xconvb + ((size_t)l*256 + r)*DI + ch0) = pk;
}

// ---- wavefront scan slot: 6 layers x 64 wgs x 256 thr; 4 batches/wg ----
// R18 structure verbatim (proven 328us): parallel gates (lanes ks=0..3 own
// batch ks), s_sleep(2) poll retry, s_setprio(1) around dot/reduce.
__global__ __launch_bounds__(256, 2) void scan_slot(
    int slot,
    const unsigned short* __restrict__ xihb,   // [NL][256][3072]
    const float* __restrict__ xz_ring,         // [NL][2][256][2048]
    const uint32_t* __restrict__ wT,           // thread-major packed f16
    const float* __restrict__ bhh,             // [NL][3072]
    uint32_t* __restrict__ hbufs,              // [NL][2][1024][4] {f16|tag}
    unsigned short* __restrict__ xoutb)        // [NL][256][1024]
{
  const int w = blockIdx.x;
  const int l = w >> 6;
  const int g = w & 63;
  const int c = slot - l;
  if (c < 0 || c >= NCH) return;

  const int tid = threadIdx.x;
  const int il  = tid >> 4;          // 0..15
  const int ks  = tid & 15;          // 0..15 (64-wide h slice)
  const int i   = g*16 + il;

  const uint32_t* pw = wT + ((size_t)(l*64 + g)*96)*256 + tid;
  uint32_t wrp[32], wzp[32], wnp[32];
  #pragma unroll
  for (int j=0;j<32;j++) wrp[j] = pw[(size_t)j*256];
  #pragma unroll
  for (int j=0;j<32;j++) wzp[j] = pw[(size_t)(32+j)*256];
  #pragma unroll
  for (int j=0;j<32;j++) wnp[j] = pw[(size_t)(64+j)*256];

  const float* bh = bhh + l*3072;
  const float bhr = bh[i], bhz = bh[DI+i], bhn = bh[2*DI+i];

  __shared__ uint32_t hshw[2][NB][16*36];   // parity, batch plane, 16 rows x 36 u32

  const uint32_t lbase = (uint32_t)l << 10;
  uint32_t* hb = hbufs + (size_t)l*2*4096;
  const unsigned short* xih = xihb + (size_t)l*256*3072;
  const float* xzp = xz_ring + ((size_t)(l*2 + (c&1))*256)*2048;
  unsigned short* xo = xoutb + (size_t)l*256*DI;

  // lane ks<4 owns batch ks: scalar x regs + scalar hprev
  float xr_c=0.f, xzg_c=0.f, xn_c=0.f, zg_c=0.f;
  float xr_n=0.f, xzg_n=0.f, xn_n=0.f, zg_n=0.f;
  float hprev = 0.f;
  if (ks < 4){
    int r = ks*64;
    xr_c  = bf2f(xih[(size_t)r*3072 + i]);
    xzg_c = bf2f(xih[(size_t)r*3072 + DI + i]);
    xn_c  = bf2f(xih[(size_t)r*3072 + 2*DI + i]);
    zg_c  = xzp[(size_t)r*2048 + DI + i];
  }

  const int r0 = tid >> 6;         // base LDS row of this thread's polled i's
  const int c0 = tid & 63;         // u16 column

  for (int dt=0; dt<CHUNK; ++dt){
    const int t   = c*CHUNK + dt;
    const int par = t & 1;
    if (t == 0){
      uint32_t* hz = &hshw[0][0][0];
      for (int j=tid; j<NB*16*36; j+=256) hz[j] = 0u;
    } else {
      const uint32_t want = lbase + (uint32_t)t;
      const uintptr_t p = (uintptr_t)(hb + (size_t)par*4096 + 4*tid);
      u32x4 A0, A1, A2, A3;
      asm volatile("global_load_dwordx4 %0, %4, off sc1\n\t"
                   "global_load_dwordx4 %1, %5, off sc1\n\t"
                   "global_load_dwordx4 %2, %6, off sc1\n\t"
                   "global_load_dwordx4 %3, %7, off sc1\n\t"
                   "s_waitcnt vmcnt(0)"
                   : "=&v"(A0), "=&v"(A1), "=&v"(A2), "=&v"(A3)
                   : "v"(p), "v"(p+4096), "v"(p+8192), "v"(p+12288));
      while (((A0[0]>>16)<want)|((A0[1]>>16)<want)|((A0[2]>>16)<want)|((A0[3]>>16)<want)|
             ((A1[0]>>16)<want)|((A1[1]>>16)<want)|((A1[2]>>16)<want)|((A1[3]>>16)<want)|
             ((A2[0]>>16)<want)|((A2[1]>>16)<want)|((A2[2]>>16)<want)|((A2[3]>>16)<want)|
             ((A3[0]>>16)<want)|((A3[1]>>16)<want)|((A3[2]>>16)<want)|((A3[3]>>16)<want)){
        __builtin_amdgcn_s_sleep(2);
        asm volatile("global_load_dwordx4 %0, %4, off sc1\n\t"
                     "global_load_dwordx4 %1, %5, off sc1\n\t"
                     "global_load_dwordx4 %2, %6, off sc1\n\t"
                     "global_load_dwordx4 %3, %7, off sc1\n\t"
                     "s_waitcnt vmcnt(0)"
                     : "=&v"(A0), "=&v"(A1), "=&v"(A2), "=&v"(A3)
                     : "v"(p), "v"(p+4096), "v"(p+8192), "v"(p+12288));
      }
      uint16_t* hp16 = (uint16_t*)&hshw[par][0][0];   // plane stride 1152 u16
      #pragma unroll
      for (int b4=0;b4<NB;b4++){
        hp16[b4*1152 + (r0+ 0)*72 + c0] = (uint16_t)A0[b4];
        hp16[b4*1152 + (r0+ 4)*72 + c0] = (uint16_t)A1[b4];
        hp16[b4*1152 + (r0+ 8)*72 + c0] = (uint16_t)A2[b4];
        hp16[b4*1152 + (r0+12)*72 + c0] = (uint16_t)A3[b4];
      }
    }
    __syncthreads();     // hshw[par] ready

    if (ks < 4 && dt == 0 && c > 0){
      const uint16_t* hp16 = (const uint16_t*)&hshw[par][0][0];
      union { uint16_t u; _Float16 h; } hv;
      hv.u = hp16[ks*1152 + (i>>6)*72 + (i&63)];
      hprev = (float)hv.h;
    }
    if (ks < 4 && dt+1 < CHUNK){
      int r = ks*64 + dt + 1;
      xr_n  = bf2f(xih[(size_t)r*3072 + i]);
      xzg_n = bf2f(xih[(size_t)r*3072 + DI + i]);
      xn_n  = bf2f(xih[(size_t)r*3072 + 2*DI + i]);
      zg_n  = xzp[(size_t)r*2048 + DI + i];
    }

    __builtin_amdgcn_s_setprio(1);
    float ar[NB] = {0,0,0,0}, az[NB] = {0,0,0,0}, an[NB] = {0,0,0,0};
    #pragma unroll
    for (int q=0;q<8;q++){
      #pragma unroll
      for (int b4=0;b4<NB;b4++){
        u32x4 hv = *(const u32x4*)&hshw[par][b4][ks*36 + 4*q];
        ar[b4] = __builtin_amdgcn_fdot2(u2h(wrp[4*q+0]), u2h(hv[0]), ar[b4], false);
        az[b4] = __builtin_amdgcn_fdot2(u2h(wzp[4*q+0]), u2h(hv[0]), az[b4], false);
        an[b4] = __builtin_amdgcn_fdot2(u2h(wnp[4*q+0]), u2h(hv[0]), an[b4], false);
        ar[b4] = __builtin_amdgcn_fdot2(u2h(wrp[4*q+1]), u2h(hv[1]), ar[b4], false);
        az[b4] = __builtin_amdgcn_fdot2(u2h(wzp[4*q+1]), u2h(hv[1]), az[b4], false);
        an[b4] = __builtin_amdgcn_fdot2(u2h(wnp[4*q+1]), u2h(hv[1]), an[b4], false);
        ar[b4] = __builtin_amdgcn_fdot2(u2h(wrp[4*q+2]), u2h(hv[2]), ar[b4], false);
        az[b4] = __builtin_amdgcn_fdot2(u2h(wzp[4*q+2]), u2h(hv[2]), az[b4], false);
        an[b4] = __builtin_amdgcn_fdot2(u2h(wnp[4*q+2]), u2h(hv[2]), an[b4], false);
        ar[b4] = __builtin_amdgcn_fdot2(u2h(wrp[4*q+3]), u2h(hv[3]), ar[b4], false);
        az[b4] = __builtin_amdgcn_fdot2(u2h(wzp[4*q+3]), u2h(hv[3]), az[b4], false);
        an[b4] = __builtin_amdgcn_fdot2(u2h(wnp[4*q+3]), u2h(hv[3]), an[b4], false);
      }
    }
    #pragma unroll
    for (int off=1; off<16; off<<=1){
      #pragma unroll
      for (int b4=0;b4<NB;b4++){
        ar[b4] += __shfl_xor(ar[b4], off);
        az[b4] += __shfl_xor(az[b4], off);
        an[b4] += __shfl_xor(an[b4], off);
      }
    }
    __builtin_amdgcn_s_setprio(0);

    if (ks < 4){
      const int b4 = ks;
      float r_ = sigmoidf_(xr_c + ar[b4] + bhr);
      float z_ = sigmoidf_(xzg_c + az[b4] + bhz);
      float n_ = tanhf_(xn_c + r_*(an[b4] + bhn));
      float hnew = (1.f - z_)*n_ + z_*hprev;
      hprev = hnew;
      uint32_t hw = (pkrtz2u(hnew, 0.f) & 0xffffu)
                  | ((lbase + (uint32_t)t + 1u) << 16);
      const uintptr_t hdst = (uintptr_t)(hb + (size_t)((t+1)&1)*4096 + 4*i + b4);
      asm volatile("global_store_dword %0, %1, off sc1"
                   :: "v"(hdst), "v"(hw));
      int r = b4*64 + dt;
      xo[(size_t)r*DI + i] = f2bf(hnew * siluf_(zg_c));
      xr_c = xr_n; xzg_c = xzg_n; xn_c = xn_n; zg_c = zg_n;
    }
  }
}

// ---------------- host ----------------
extern "C" void kernel_launch(void* const* d_in, const int* in_sizes, int n_in,
                              void* d_out, int out_size, void* d_ws, size_t ws_size,
                              hipStream_t stream)
{
  (void)in_sizes; (void)n_in; (void)out_size; (void)ws_size;
  const float* x      = (const float*)d_in[0];
  const float* norm_w = (const float*)d_in[1];
  const float* norm_b = (const float*)d_in[2];
  const float* inw    = (const float*)d_in[3];
  const float* inb    = (const float*)d_in[4];
  const float* convw  = (const float*)d_in[5];
  const float* convb  = (const float*)d_in[6];
  const float* wih    = (const float*)d_in[7];
  const float* whh    = (const float*)d_in[8];
  const float* bih    = (const float*)d_in[9];
  const float* bhh    = (const float*)d_in[10];
  const float* outw   = (const float*)d_in[11];
  const float* outb   = (const float*)d_in[12];
  const float* normfw = (const float*)d_in[13];
  const float* normfb = (const float*)d_in[14];
  float* out = (float*)d_out;

  char* ws = (char*)d_ws;
  size_t off = 0;
  auto alloc = [&](size_t bytes)->void*{ void* p = ws + off; off = (off + bytes + 255) & ~(size_t)255; return p; };
  uint32_t*       wT      = (uint32_t*)      alloc((size_t)NL*64*96*256*4);
  unsigned short* wihbf   = (unsigned short*)alloc((size_t)NL*3072*1024*2);   // +37.7MB
  unsigned short* lnbf    = (unsigned short*)alloc((size_t)NL*256*DM*2);
  float*          xz_ring = (float*)         alloc((size_t)NL*2*256*2048*4);
  unsigned short* xconvb  = (unsigned short*)alloc((size_t)NL*256*DI*2);
  unsigned short* xihb    = (unsigned short*)alloc((size_t)NL*256*3072*2);
  unsigned short* xoutb   = (unsigned short*)alloc((size_t)NL*256*DI*2);
  float*          resid_ring  = (float*)     alloc((size_t)NL*2*256*DM*4);
  float*          hidden_ring = (float*)     alloc((size_t)NL*2*256*DM*4);
  float*          resid5  = (float*)         alloc((size_t)BT*DM*4);
  float*          hidden5 = (float*)         alloc((size_t)BT*DM*4);
  uint32_t*       hbufs   = (uint32_t*)      alloc((size_t)NL*2*4096*4);

  hipMemsetAsync(hbufs, 0, (size_t)NL*2*4096*4, stream);
  cvtwt_kernel<<<2048, 256, 0, stream>>>(whh, wT);
  cvtbf_kernel<<<2048, 256, 0, stream>>>(wih, wihbf, NL*3072*1024);

  for (int slot = 0; slot < NSLOT; ++slot){
    lnres_slot<<<dim3(64,1,NL), 256, 0, stream>>>(slot, x, norm_w, norm_b,
                                                  hidden_ring, resid_ring, resid5, lnbf);
    gemm_slot<<<dim3(16,2,NL), 256, 0, stream>>>(0, slot, lnbf, inw, inb, xz_ring,
                                                 xconvb, wihbf, bih, xihb,
                                                 xoutb, outw, outb, hidden_ring, hidden5);
    conv_slot<<<dim3(128,1,NL), 256, 0, stream>>>(slot, xz_ring, convw, convb, xconvb);
    gemm_slot<<<dim3(24,2,NL), 256, 0, stream>>>(1, slot, lnbf, inw, inb, xz_ring,
                                                 xconvb, wihbf, bih, xihb,
                                                 xoutb, outw, outb, hidden_ring, hidden5);
    scan_slot<<<dim3(NL*64), 256, 0, stream>>>(slot, xihb, xz_ring, wT, bhh, hbufs, xoutb);
    gemm_slot<<<dim3(4,2,NL), 256, 0, stream>>>(2, slot, lnbf, inw, inb, xz_ring,
                                                xconvb, wihbf, bih, xihb,
                                                xoutb, outw, outb, hidden_ring, hidden5);
  }
  ln_final<<<1024, 256, 0, stream>>>(hidden5, resid5, normfw, normfb, out);
}